// Round 9
// baseline (1011.966 us; speedup 1.0000x reference)
//
#include <hip/hip_runtime.h>

constexpr int NN = 150000;   // nodes
constexpr int NE = 4800000;  // edges
constexpr int NG = 512;      // graphs
constexpr int H  = 16;       // hidden
constexpr int NB   = 1024;   // coarse dst-buckets
constexpr int NPBK = 147;    // nodes per bucket (ceil NN/NB)
constexpr int NBLK = 256;    // streaming blocks for hist/bucket
constexpr int CHUNK = (NE + NBLK - 1) / NBLK;   // 18750 edges per block

__device__ inline unsigned short f2bf(float f) {
    union { float f; unsigned u; } v; v.f = f;
    unsigned r = v.u + 0x7FFFu + ((v.u >> 16) & 1u);   // RNE
    return (unsigned short)(r >> 16);
}
__device__ inline float bf2f(unsigned short s) {
    union { unsigned u; float f; } v; v.u = ((unsigned)s) << 16;
    return v.f;
}

// ---------- phase A: per-block LDS histogram of dst buckets ----------
__global__ void k_hist(const int* __restrict__ dst, int* __restrict__ mat) {
    __shared__ int cnt[NB];
    for (int t = threadIdx.x; t < NB; t += 256) cnt[t] = 0;
    __syncthreads();
    int b = blockIdx.x;
    int e0 = b * CHUNK, e1 = min(e0 + CHUNK, NE);
    for (int e = e0 + (int)threadIdx.x; e < e1; e += 256)
        atomicAdd(&cnt[dst[e] / NPBK], 1);
    __syncthreads();
    for (int t = threadIdx.x; t < NB; t += 256) mat[b * NB + t] = cnt[t];
}

// ---------- column scan: mat[:,j] -> exclusive prefix, totals ----------
__global__ void k_scanb(int* __restrict__ mat, int* __restrict__ tot) {
    __shared__ int tmp[NBLK];
    int j = blockIdx.x, t = threadIdx.x;
    int v = mat[t * NB + j];
    tmp[t] = v;
    __syncthreads();
    for (int off = 1; off < NBLK; off <<= 1) {
        int a = (t >= off) ? tmp[t - off] : 0;
        __syncthreads();
        tmp[t] += a;
        __syncthreads();
    }
    mat[t * NB + j] = tmp[t] - v;               // exclusive within column
    if (t == NBLK - 1) tot[j] = tmp[t];
}

// ---------- bucket base scan (exclusive over 1024 buckets) ----------
__global__ void k_scant(const int* __restrict__ tot, int* __restrict__ base) {
    __shared__ int tmp[NB];
    int t = threadIdx.x;
    int v = tot[t];
    tmp[t] = v;
    __syncthreads();
    for (int off = 1; off < NB; off <<= 1) {
        int a = (t >= off) ? tmp[t - off] : 0;
        __syncthreads();
        tmp[t] += a;
        __syncthreads();
    }
    base[t] = tmp[t] - v;
    if (t == 0) base[NB] = NE;
}

// ---------- phase B: packed (src | local_dst<<18) grouped by bucket ----------
__global__ void k_bucket(const int* __restrict__ src, const int* __restrict__ dst,
                         const int* __restrict__ mat, const int* __restrict__ base,
                         unsigned* __restrict__ ed) {
    __shared__ int cur[NB];
    int b = blockIdx.x;
    for (int t = threadIdx.x; t < NB; t += 256) cur[t] = base[t] + mat[b * NB + t];
    __syncthreads();
    int e0 = b * CHUNK, e1 = min(e0 + CHUNK, NE);
    for (int e = e0 + (int)threadIdx.x; e < e1; e += 256) {
        int d = dst[e];
        int bq = d / NPBK;
        int p = atomicAdd(&cur[bq], 1);
        ed[p] = (unsigned)src[e] | ((unsigned)(d - bq * NPBK) << 18);
    }
}

// ---------- per-bucket degree -> disq (LDS count) ----------
__global__ void k_disq_b(const unsigned* __restrict__ ed, const int* __restrict__ base,
                         float* __restrict__ disq) {
    __shared__ int cnt[NPBK];
    int j = blockIdx.x;
    for (int t = threadIdx.x; t < NPBK; t += 256) cnt[t] = 0;
    __syncthreads();
    int n0 = j * NPBK;
    int e0 = base[j], e1 = base[j + 1];
    for (int e = e0 + (int)threadIdx.x; e < e1; e += 256)
        atomicAdd(&cnt[ed[e] >> 18], 1);
    __syncthreads();
    for (int t = threadIdx.x; t < NPBK; t += 256) {
        int n = n0 + t;
        if (n < NN) disq[n] = rsqrtf((float)(cnt[t] + 1));
    }
}

// ---------- y = (x @ W1) * disq  -> bf16 ----------
__global__ void k_xw1(const float* __restrict__ x, const float* __restrict__ W1,
                      const float* __restrict__ disq, unsigned short* __restrict__ y) {
    __shared__ float w[4 * H];
    if (threadIdx.x < 4 * H) w[threadIdx.x] = W1[threadIdx.x];
    __syncthreads();
    int i = blockIdx.x * blockDim.x + threadIdx.x;
    if (i >= NN) return;
    float4 xv = ((const float4*)x)[i];
    float d = disq[i];
    float o[H];
#pragma unroll
    for (int h = 0; h < H; ++h)
        o[h] = (xv.x * w[0*H + h] + xv.y * w[1*H + h] +
                xv.z * w[2*H + h] + xv.w * w[3*H + h]) * d;
    unsigned pk[8];
#pragma unroll
    for (int q = 0; q < 8; ++q)
        pk[q] = (unsigned)f2bf(o[2*q]) | ((unsigned)f2bf(o[2*q+1]) << 16);
    uint4* yp = (uint4*)(y + (size_t)i * H);
    yp[0] = make_uint4(pk[0], pk[1], pk[2], pk[3]);
    yp[1] = make_uint4(pk[4], pk[5], pk[6], pk[7]);
}

// ---------- phase C: per-bucket LDS accumulate + fused epilogue (512 thr) ----------
// h[n] = relu(disq[n] * (y[n] + sum_{e:dst=n} y[src_e]) + b)
__global__ void k_conv(const unsigned* __restrict__ ed, const int* __restrict__ base,
                       const unsigned short* __restrict__ y, const float* __restrict__ disq,
                       const float* __restrict__ bias, float* __restrict__ hout) {
    __shared__ float acc[NPBK * H];     // 9408 B
    __shared__ float bs[H];
    if (threadIdx.x < H) bs[threadIdx.x] = bias[threadIdx.x];
    for (int t = threadIdx.x; t < NPBK * H; t += 512) acc[t] = 0.f;
    __syncthreads();
    int j = blockIdx.x;
    int n0 = j * NPBK;
    int e0 = base[j], e1 = base[j + 1];
    int lane = threadIdx.x & (H - 1);
    int grp  = threadIdx.x >> 4;        // 32 edge-groups per block
    for (int e = e0 + grp; e < e1; e += 32) {
        unsigned ee = ed[e];
        float v = bf2f(y[(size_t)(ee & 0x3FFFFu) * H + lane]);
        atomicAdd(&acc[(ee >> 18) * H + lane], v);
    }
    __syncthreads();
    for (int t = grp; t < NPBK; t += 32) {
        int n = n0 + t;
        if (n >= NN) break;
        float a = acc[t * H + lane] + bf2f(y[(size_t)n * H + lane]);
        hout[(size_t)n * H + lane] = fmaxf(fmaf(a, disq[n], bs[lane]), 0.f);
    }
}

// ---------- y = (h @ W2) * disq -> bf16 ----------
__global__ void k_hw2(const float* __restrict__ hin, const float* __restrict__ W2,
                      const float* __restrict__ disq, unsigned short* __restrict__ yout) {
    __shared__ float w[H * H];
    if (threadIdx.x < H * H) w[threadIdx.x] = W2[threadIdx.x];
    __syncthreads();
    int i = blockIdx.x * blockDim.x + threadIdx.x;
    if (i >= NN) return;
    float hv[H];
    const float4* hp = (const float4*)(hin + (size_t)i * H);
#pragma unroll
    for (int q = 0; q < 4; ++q) ((float4*)hv)[q] = hp[q];
    float d = disq[i];
    float o[H];
#pragma unroll
    for (int h = 0; h < H; ++h) {
        float s = 0.f;
#pragma unroll
        for (int k = 0; k < H; ++k) s += hv[k] * w[k*H + h];
        o[h] = s * d;
    }
    unsigned pk[8];
#pragma unroll
    for (int q = 0; q < 8; ++q)
        pk[q] = (unsigned)f2bf(o[2*q]) | ((unsigned)f2bf(o[2*q+1]) << 16);
    uint4* yp = (uint4*)(yout + (size_t)i * H);
    yp[0] = make_uint4(pk[0], pk[1], pk[2], pk[3]);
    yp[1] = make_uint4(pk[4], pk[5], pk[6], pk[7]);
}

// ---------- pool: batch sorted -> binary-search segmented sum ----------
__global__ void k_pool_seg(const float* __restrict__ h, const int* __restrict__ batch,
                           float* __restrict__ gout) {
    int g    = blockIdx.x * (blockDim.x / H) + threadIdx.x / H;
    int lane = threadIdx.x & (H - 1);
    if (g >= NG) return;
    int lo = 0, hi = NN;
    while (lo < hi) { int m = (lo + hi) >> 1; if (batch[m] < g) lo = m + 1; else hi = m; }
    int start = lo;
    hi = NN;
    while (lo < hi) { int m = (lo + hi) >> 1; if (batch[m] < g + 1) lo = m + 1; else hi = m; }
    int end = lo;
    float acc = 0.f;
    for (int i = start; i < end; ++i) acc += h[(size_t)i * H + lane];
    gout[(size_t)g * H + lane] = acc;
}

// ---------- final MLP ----------
__global__ void k_mlp(const float* __restrict__ g, const float* __restrict__ Wf1,
                      const float* __restrict__ bf1, const float* __restrict__ Wf2,
                      const float* __restrict__ bf2, float* __restrict__ out) {
    __shared__ float w1[H * H];
    __shared__ float b1s[H];
    __shared__ float w2[H];
    __shared__ float b2s;
    if (threadIdx.x < H * H) w1[threadIdx.x] = Wf1[threadIdx.x];
    if (threadIdx.x < H) { b1s[threadIdx.x] = bf1[threadIdx.x]; w2[threadIdx.x] = Wf2[threadIdx.x]; }
    if (threadIdx.x == 0) b2s = bf2[0];
    __syncthreads();
    int i = blockIdx.x * blockDim.x + threadIdx.x;
    if (i >= NG) return;
    float gv[H];
    const float4* gp = (const float4*)(g + (size_t)i * H);
#pragma unroll
    for (int q = 0; q < 4; ++q) ((float4*)gv)[q] = gp[q];
    float s2 = 0.f;
#pragma unroll
    for (int h = 0; h < H; ++h) {
        float t = b1s[h];
#pragma unroll
        for (int k = 0; k < H; ++k) t += gv[k] * w1[k*H + h];
        s2 += fmaxf(t, 0.f) * w2[h];
    }
    out[i] = s2 + b2s;
}

// ================= fallback (baseline atomic path, f32) =================
__global__ void k_deg_init(float* __restrict__ deg) {
    int i = blockIdx.x * blockDim.x + threadIdx.x;
    if (i < NN) deg[i] = 1.0f;
}
__global__ void k_deg_edges(const int* __restrict__ dst, float* __restrict__ deg) {
    int i = blockIdx.x * blockDim.x + threadIdx.x;
    if (i < NE) atomicAdd(&deg[dst[i]], 1.0f);
}
__global__ void k_disq(float* __restrict__ deg) {
    int i = blockIdx.x * blockDim.x + threadIdx.x;
    if (i < NN) deg[i] = rsqrtf(deg[i]);
}
__global__ void k_xw1f(const float* __restrict__ x, const float* __restrict__ W1,
                       const float* __restrict__ disq, float* __restrict__ y) {
    __shared__ float w[4 * H];
    if (threadIdx.x < 4 * H) w[threadIdx.x] = W1[threadIdx.x];
    __syncthreads();
    int i = blockIdx.x * blockDim.x + threadIdx.x;
    if (i >= NN) return;
    float4 xv = ((const float4*)x)[i];
    float d = disq[i];
    float o[H];
#pragma unroll
    for (int h = 0; h < H; ++h)
        o[h] = (xv.x * w[0*H + h] + xv.y * w[1*H + h] +
                xv.z * w[2*H + h] + xv.w * w[3*H + h]) * d;
    float4* yp = (float4*)(y + (size_t)i * H);
#pragma unroll
    for (int q = 0; q < 4; ++q) yp[q] = ((float4*)o)[q];
}
__global__ void k_hw2f(const float* __restrict__ hin, const float* __restrict__ W2,
                       const float* __restrict__ disq, float* __restrict__ yout) {
    __shared__ float w[H * H];
    if (threadIdx.x < H * H) w[threadIdx.x] = W2[threadIdx.x];
    __syncthreads();
    int i = blockIdx.x * blockDim.x + threadIdx.x;
    if (i >= NN) return;
    float hv[H];
    const float4* hp = (const float4*)(hin + (size_t)i * H);
#pragma unroll
    for (int q = 0; q < 4; ++q) ((float4*)hv)[q] = hp[q];
    float d = disq[i];
    float o[H];
#pragma unroll
    for (int h = 0; h < H; ++h) {
        float s = 0.f;
#pragma unroll
        for (int k = 0; k < H; ++k) s += hv[k] * w[k*H + h];
        o[h] = s * d;
    }
    float4* yp = (float4*)(yout + (size_t)i * H);
#pragma unroll
    for (int q = 0; q < 4; ++q) yp[q] = ((float4*)o)[q];
}
__global__ void k_scatter(const int* __restrict__ src, const int* __restrict__ dst,
                          const float* __restrict__ y, float* __restrict__ acc) {
    int i = blockIdx.x * blockDim.x + threadIdx.x;
    if (i >= NE) return;
    int s = src[i], d = dst[i];
    const float4* yp = (const float4*)(y + (size_t)s * H);
    float* ap = acc + (size_t)d * H;
#pragma unroll
    for (int q = 0; q < 4; ++q) {
        float4 v = yp[q];
        atomicAdd(ap + q*4 + 0, v.x);
        atomicAdd(ap + q*4 + 1, v.y);
        atomicAdd(ap + q*4 + 2, v.z);
        atomicAdd(ap + q*4 + 3, v.w);
    }
}
__global__ void k_post(const float* __restrict__ acc, const float* __restrict__ disq,
                       const float* __restrict__ b, float* __restrict__ hout) {
    __shared__ float bs[H];
    if (threadIdx.x < H) bs[threadIdx.x] = b[threadIdx.x];
    __syncthreads();
    int i = blockIdx.x * blockDim.x + threadIdx.x;
    if (i >= NN) return;
    float d = disq[i];
    const float4* ap = (const float4*)(acc + (size_t)i * H);
    float4* hp = (float4*)(hout + (size_t)i * H);
#pragma unroll
    for (int q = 0; q < 4; ++q) {
        float4 v = ap[q];
        float4 r;
        r.x = fmaxf(v.x * d + bs[q*4+0], 0.f);
        r.y = fmaxf(v.y * d + bs[q*4+1], 0.f);
        r.z = fmaxf(v.z * d + bs[q*4+2], 0.f);
        r.w = fmaxf(v.w * d + bs[q*4+3], 0.f);
        hp[q] = r;
    }
}

extern "C" void kernel_launch(void* const* d_in, const int* in_sizes, int n_in,
                              void* d_out, int out_size, void* d_ws, size_t ws_size,
                              hipStream_t stream) {
    const float* x   = (const float*)d_in[0];
    const float* W1  = (const float*)d_in[1];
    const float* b1  = (const float*)d_in[2];
    const float* W2  = (const float*)d_in[3];
    const float* b2  = (const float*)d_in[4];
    const float* Wf1 = (const float*)d_in[5];
    const float* bf1 = (const float*)d_in[6];
    const float* Wf2 = (const float*)d_in[7];
    const float* bf2 = (const float*)d_in[8];
    const int*   ei    = (const int*)d_in[9];
    const int*   batch = (const int*)d_in[10];
    const int* src = ei;        // edge_index row 0
    const int* dst = ei + NE;   // edge_index row 1
    float* out = (float*)d_out;

    const int BT  = 256;
    const int gbN = (NN + BT - 1) / BT;               // 586
    const int gbE = (NE + BT - 1) / BT;               // 18750 (fallback)
    const int NPB = BT / H;                           // 16
    const int gbP = (NG + NPB - 1) / NPB;             // 32

    // ---- workspace layout (4-byte units; region starts 16B-aligned) ----
    // mat[256*1024] | tot[1024] | base[1025]pad | ed[NE] packed u32 |
    // disq[NN] | ybf[NN*H bf16 = 1.2M words] | bufB[NN*H f32] | g[NG*H]
    size_t need = ((size_t)8822400) * 4;   // ~35.3 MB
    if (ws_size >= need) {
        int*      mat  = (int*)d_ws;                   // 262144
        int*      tot  = mat + 262144;                 // 1024
        int*      base = mat + 263168;                 // 1025 (pad to 264208)
        unsigned* ed   = (unsigned*)(mat + 264208);    // NE words
        float*    disq = (float*)(mat + 5064208);
        unsigned short* ybf = (unsigned short*)(mat + 5214208); // 1.2M words
        float*    bufB = (float*)(mat + 6414208);
        float*    g    = (float*)(mat + 8814208);

        // graph bucketing (no global atomics)
        k_hist  <<<NBLK, 256, 0, stream>>>(dst, mat);
        k_scanb <<<NB,   NBLK, 0, stream>>>(mat, tot);
        k_scant <<<1,    NB,  0, stream>>>(tot, base);
        k_bucket<<<NBLK, 256, 0, stream>>>(src, dst, mat, base, ed);
        k_disq_b<<<NB,   256, 0, stream>>>(ed, base, disq);

        // conv1
        k_xw1 <<<gbN, 256, 0, stream>>>(x, W1, disq, ybf);
        k_conv<<<NB,  512, 0, stream>>>(ed, base, ybf, disq, b1, bufB);   // h1
        // conv2
        k_hw2 <<<gbN, 256, 0, stream>>>(bufB, W2, disq, ybf);             // y2
        k_conv<<<NB,  512, 0, stream>>>(ed, base, ybf, disq, b2, bufB);   // h2
        // pool + MLP
        k_pool_seg<<<gbP, 256, 0, stream>>>(bufB, batch, g);
        k_mlp<<<1, 512, 0, stream>>>(g, Wf1, bf1, Wf2, bf2, out);
    } else {
        // fallback: baseline atomic-scatter path (~20 MB ws, f32)
        float* disq = (float*)d_ws;
        float* bufA = disq + NN;
        float* bufB = bufA + (size_t)NN * H;
        float* g    = bufB + (size_t)NN * H;

        k_deg_init<<<gbN, BT, 0, stream>>>(disq);
        k_deg_edges<<<gbE, BT, 0, stream>>>(dst, disq);
        k_disq<<<gbN, BT, 0, stream>>>(disq);

        k_xw1f<<<gbN, BT, 0, stream>>>(x, W1, disq, bufA);
        hipMemcpyAsync(bufB, bufA, (size_t)NN * H * sizeof(float),
                       hipMemcpyDeviceToDevice, stream);
        k_scatter<<<gbE, BT, 0, stream>>>(src, dst, bufA, bufB);
        k_post<<<gbN, BT, 0, stream>>>(bufB, disq, b1, bufA);

        k_hw2f<<<gbN, BT, 0, stream>>>(bufA, W2, disq, bufB);
        hipMemcpyAsync(bufA, bufB, (size_t)NN * H * sizeof(float),
                       hipMemcpyDeviceToDevice, stream);
        k_scatter<<<gbE, BT, 0, stream>>>(src, dst, bufB, bufA);
        k_post<<<gbN, BT, 0, stream>>>(bufA, disq, b2, bufB);

        k_pool_seg<<<gbP, BT, 0, stream>>>(bufB, batch, g);
        k_mlp<<<1, 512, 0, stream>>>(g, Wf1, bf1, Wf2, bf2, out);
    }
}

// Round 10
// 341.832 us; speedup vs baseline: 2.9604x; 2.9604x over previous
//
#include <hip/hip_runtime.h>

constexpr int NN = 150000;   // nodes
constexpr int NE = 4800000;  // edges
constexpr int NG = 512;      // graphs
constexpr int H  = 16;       // hidden
constexpr int NB   = 1024;   // coarse dst-buckets
constexpr int NPBK = 147;    // nodes per bucket (ceil NN/NB)
constexpr int NBLK = 256;    // streaming blocks for hist/bucket
constexpr int CHUNK = (NE + NBLK - 1) / NBLK;   // 18750 edges per block

__device__ inline unsigned short f2bf(float f) {
    union { float f; unsigned u; } v; v.f = f;
    unsigned r = v.u + 0x7FFFu + ((v.u >> 16) & 1u);   // RNE
    return (unsigned short)(r >> 16);
}
__device__ inline float bf2f(unsigned short s) {
    union { unsigned u; float f; } v; v.u = ((unsigned)s) << 16;
    return v.f;
}

// ---------- phase A: per-block LDS histogram of dst buckets ----------
__global__ void k_hist(const int* __restrict__ dst, int* __restrict__ mat) {
    __shared__ int cnt[NB];
    for (int t = threadIdx.x; t < NB; t += 256) cnt[t] = 0;
    __syncthreads();
    int b = blockIdx.x;
    int e0 = b * CHUNK, e1 = min(e0 + CHUNK, NE);
    for (int e = e0 + (int)threadIdx.x; e < e1; e += 256)
        atomicAdd(&cnt[dst[e] / NPBK], 1);
    __syncthreads();
    for (int t = threadIdx.x; t < NB; t += 256) mat[b * NB + t] = cnt[t];
}

// ---------- column scan: mat[:,j] -> exclusive prefix, totals ----------
__global__ void k_scanb(int* __restrict__ mat, int* __restrict__ tot) {
    __shared__ int tmp[NBLK];
    int j = blockIdx.x, t = threadIdx.x;
    int v = mat[t * NB + j];
    tmp[t] = v;
    __syncthreads();
    for (int off = 1; off < NBLK; off <<= 1) {
        int a = (t >= off) ? tmp[t - off] : 0;
        __syncthreads();
        tmp[t] += a;
        __syncthreads();
    }
    mat[t * NB + j] = tmp[t] - v;               // exclusive within column
    if (t == NBLK - 1) tot[j] = tmp[t];
}

// ---------- bucket base scan (exclusive over 1024 buckets) ----------
__global__ void k_scant(const int* __restrict__ tot, int* __restrict__ base) {
    __shared__ int tmp[NB];
    int t = threadIdx.x;
    int v = tot[t];
    tmp[t] = v;
    __syncthreads();
    for (int off = 1; off < NB; off <<= 1) {
        int a = (t >= off) ? tmp[t - off] : 0;
        __syncthreads();
        tmp[t] += a;
        __syncthreads();
    }
    base[t] = tmp[t] - v;
    if (t == 0) base[NB] = NE;
}

// ---------- phase B: packed (src | local_dst<<18) grouped by bucket ----------
__global__ void k_bucket(const int* __restrict__ src, const int* __restrict__ dst,
                         const int* __restrict__ mat, const int* __restrict__ base,
                         unsigned* __restrict__ ed) {
    __shared__ int cur[NB];
    int b = blockIdx.x;
    for (int t = threadIdx.x; t < NB; t += 256) cur[t] = base[t] + mat[b * NB + t];
    __syncthreads();
    int e0 = b * CHUNK, e1 = min(e0 + CHUNK, NE);
    for (int e = e0 + (int)threadIdx.x; e < e1; e += 256) {
        int d = dst[e];
        int bq = d / NPBK;
        int p = atomicAdd(&cur[bq], 1);
        ed[p] = (unsigned)src[e] | ((unsigned)(d - bq * NPBK) << 18);
    }
}

// ---------- phase B2: per-bucket counting sort by local dst -> full CSR + disq ----------
__global__ void k_csr(const unsigned* __restrict__ ed, const int* __restrict__ base,
                      int* __restrict__ rs, int* __restrict__ csr,
                      float* __restrict__ disq) {
    __shared__ int cnt[256];
    __shared__ int scn[256];
    int j = blockIdx.x, t = threadIdx.x;
    cnt[t] = 0;
    __syncthreads();
    int e0 = base[j], e1 = base[j + 1];
    for (int e = e0 + t; e < e1; e += 256)
        atomicAdd(&cnt[ed[e] >> 18], 1);
    __syncthreads();
    int v = cnt[t];
    scn[t] = v;
    __syncthreads();
    for (int off = 1; off < 256; off <<= 1) {
        int a = (t >= off) ? scn[t - off] : 0;
        __syncthreads();
        scn[t] += a;
        __syncthreads();
    }
    int excl = scn[t] - v;                       // exclusive scan
    int n0 = j * NPBK;
    if (t < NPBK && n0 + t < NN) {
        rs[n0 + t] = e0 + excl;
        disq[n0 + t] = rsqrtf((float)(v + 1));   // +1 self-loop
    }
    cnt[t] = excl;                               // reuse as cursor
    __syncthreads();
    for (int e = e0 + t; e < e1; e += 256) {
        unsigned ee = ed[e];
        int p = atomicAdd(&cnt[ee >> 18], 1);
        csr[e0 + p] = (int)(ee & 0x3FFFFu);
    }
    if (j == 0 && t == 0) rs[NN] = NE;
}

// ---------- y = (x @ W1) * disq  -> bf16 ----------
__global__ void k_xw1(const float* __restrict__ x, const float* __restrict__ W1,
                      const float* __restrict__ disq, unsigned short* __restrict__ y) {
    __shared__ float w[4 * H];
    if (threadIdx.x < 4 * H) w[threadIdx.x] = W1[threadIdx.x];
    __syncthreads();
    int i = blockIdx.x * blockDim.x + threadIdx.x;
    if (i >= NN) return;
    float4 xv = ((const float4*)x)[i];
    float d = disq[i];
    float o[H];
#pragma unroll
    for (int h = 0; h < H; ++h)
        o[h] = (xv.x * w[0*H + h] + xv.y * w[1*H + h] +
                xv.z * w[2*H + h] + xv.w * w[3*H + h]) * d;
    unsigned pk[8];
#pragma unroll
    for (int q = 0; q < 8; ++q)
        pk[q] = (unsigned)f2bf(o[2*q]) | ((unsigned)f2bf(o[2*q+1]) << 16);
    uint4* yp = (uint4*)(y + (size_t)i * H);
    yp[0] = make_uint4(pk[0], pk[1], pk[2], pk[3]);
    yp[1] = make_uint4(pk[4], pk[5], pk[6], pk[7]);
}

// ---------- gather: 16 lanes/node, 8-way unrolled for MLP ----------
// h[n] = relu(disq[n] * (y[n] + sum y[csr]) + b)
__global__ void k_gather(const int* __restrict__ rs, const int* __restrict__ csr,
                         const unsigned short* __restrict__ y, const float* __restrict__ disq,
                         const float* __restrict__ b, float* __restrict__ hout) {
    int n    = blockIdx.x * 16 + (threadIdx.x >> 4);
    int lane = threadIdx.x & 15;
    if (n >= NN) return;
    int s0 = rs[n], s1 = rs[n + 1];
    float acc = bf2f(y[(size_t)n * H + lane]);   // self-loop term
    int k = s0;
    for (; k + 8 <= s1; k += 8) {
        int sa = csr[k+0], sb = csr[k+1], sc = csr[k+2], sd = csr[k+3];
        int se = csr[k+4], sf = csr[k+5], sg = csr[k+6], sh = csr[k+7];
        float v0 = bf2f(y[(size_t)sa * H + lane]);
        float v1 = bf2f(y[(size_t)sb * H + lane]);
        float v2 = bf2f(y[(size_t)sc * H + lane]);
        float v3 = bf2f(y[(size_t)sd * H + lane]);
        float v4 = bf2f(y[(size_t)se * H + lane]);
        float v5 = bf2f(y[(size_t)sf * H + lane]);
        float v6 = bf2f(y[(size_t)sg * H + lane]);
        float v7 = bf2f(y[(size_t)sh * H + lane]);
        acc += ((v0 + v1) + (v2 + v3)) + ((v4 + v5) + (v6 + v7));
    }
    for (; k < s1; ++k) acc += bf2f(y[(size_t)csr[k] * H + lane]);
    hout[(size_t)n * H + lane] = fmaxf(fmaf(acc, disq[n], b[lane]), 0.f);
}

// ---------- y = (h @ W2) * disq -> bf16 ----------
__global__ void k_hw2(const float* __restrict__ hin, const float* __restrict__ W2,
                      const float* __restrict__ disq, unsigned short* __restrict__ yout) {
    __shared__ float w[H * H];
    if (threadIdx.x < H * H) w[threadIdx.x] = W2[threadIdx.x];
    __syncthreads();
    int i = blockIdx.x * blockDim.x + threadIdx.x;
    if (i >= NN) return;
    float hv[H];
    const float4* hp = (const float4*)(hin + (size_t)i * H);
#pragma unroll
    for (int q = 0; q < 4; ++q) ((float4*)hv)[q] = hp[q];
    float d = disq[i];
    float o[H];
#pragma unroll
    for (int h = 0; h < H; ++h) {
        float s = 0.f;
#pragma unroll
        for (int k = 0; k < H; ++k) s += hv[k] * w[k*H + h];
        o[h] = s * d;
    }
    unsigned pk[8];
#pragma unroll
    for (int q = 0; q < 8; ++q)
        pk[q] = (unsigned)f2bf(o[2*q]) | ((unsigned)f2bf(o[2*q+1]) << 16);
    uint4* yp = (uint4*)(yout + (size_t)i * H);
    yp[0] = make_uint4(pk[0], pk[1], pk[2], pk[3]);
    yp[1] = make_uint4(pk[4], pk[5], pk[6], pk[7]);
}

// ---------- pool: batch sorted -> binary-search segmented sum ----------
__global__ void k_pool_seg(const float* __restrict__ h, const int* __restrict__ batch,
                           float* __restrict__ gout) {
    int g    = blockIdx.x * (blockDim.x / H) + threadIdx.x / H;
    int lane = threadIdx.x & (H - 1);
    if (g >= NG) return;
    int lo = 0, hi = NN;
    while (lo < hi) { int m = (lo + hi) >> 1; if (batch[m] < g) lo = m + 1; else hi = m; }
    int start = lo;
    hi = NN;
    while (lo < hi) { int m = (lo + hi) >> 1; if (batch[m] < g + 1) lo = m + 1; else hi = m; }
    int end = lo;
    float acc = 0.f;
    for (int i = start; i < end; ++i) acc += h[(size_t)i * H + lane];
    gout[(size_t)g * H + lane] = acc;
}

// ---------- final MLP ----------
__global__ void k_mlp(const float* __restrict__ g, const float* __restrict__ Wf1,
                      const float* __restrict__ bf1, const float* __restrict__ Wf2,
                      const float* __restrict__ bf2, float* __restrict__ out) {
    __shared__ float w1[H * H];
    __shared__ float b1s[H];
    __shared__ float w2[H];
    __shared__ float b2s;
    if (threadIdx.x < H * H) w1[threadIdx.x] = Wf1[threadIdx.x];
    if (threadIdx.x < H) { b1s[threadIdx.x] = bf1[threadIdx.x]; w2[threadIdx.x] = Wf2[threadIdx.x]; }
    if (threadIdx.x == 0) b2s = bf2[0];
    __syncthreads();
    int i = blockIdx.x * blockDim.x + threadIdx.x;
    if (i >= NG) return;
    float gv[H];
    const float4* gp = (const float4*)(g + (size_t)i * H);
#pragma unroll
    for (int q = 0; q < 4; ++q) ((float4*)gv)[q] = gp[q];
    float s2 = 0.f;
#pragma unroll
    for (int h = 0; h < H; ++h) {
        float t = b1s[h];
#pragma unroll
        for (int k = 0; k < H; ++k) t += gv[k] * w1[k*H + h];
        s2 += fmaxf(t, 0.f) * w2[h];
    }
    out[i] = s2 + b2s;
}

// ================= fallback (baseline atomic path, f32) =================
__global__ void k_deg_init(float* __restrict__ deg) {
    int i = blockIdx.x * blockDim.x + threadIdx.x;
    if (i < NN) deg[i] = 1.0f;
}
__global__ void k_deg_edges(const int* __restrict__ dst, float* __restrict__ deg) {
    int i = blockIdx.x * blockDim.x + threadIdx.x;
    if (i < NE) atomicAdd(&deg[dst[i]], 1.0f);
}
__global__ void k_disq(float* __restrict__ deg) {
    int i = blockIdx.x * blockDim.x + threadIdx.x;
    if (i < NN) deg[i] = rsqrtf(deg[i]);
}
__global__ void k_xw1f(const float* __restrict__ x, const float* __restrict__ W1,
                       const float* __restrict__ disq, float* __restrict__ y) {
    __shared__ float w[4 * H];
    if (threadIdx.x < 4 * H) w[threadIdx.x] = W1[threadIdx.x];
    __syncthreads();
    int i = blockIdx.x * blockDim.x + threadIdx.x;
    if (i >= NN) return;
    float4 xv = ((const float4*)x)[i];
    float d = disq[i];
    float o[H];
#pragma unroll
    for (int h = 0; h < H; ++h)
        o[h] = (xv.x * w[0*H + h] + xv.y * w[1*H + h] +
                xv.z * w[2*H + h] + xv.w * w[3*H + h]) * d;
    float4* yp = (float4*)(y + (size_t)i * H);
#pragma unroll
    for (int q = 0; q < 4; ++q) yp[q] = ((float4*)o)[q];
}
__global__ void k_hw2f(const float* __restrict__ hin, const float* __restrict__ W2,
                       const float* __restrict__ disq, float* __restrict__ yout) {
    __shared__ float w[H * H];
    if (threadIdx.x < H * H) w[threadIdx.x] = W2[threadIdx.x];
    __syncthreads();
    int i = blockIdx.x * blockDim.x + threadIdx.x;
    if (i >= NN) return;
    float hv[H];
    const float4* hp = (const float4*)(hin + (size_t)i * H);
#pragma unroll
    for (int q = 0; q < 4; ++q) ((float4*)hv)[q] = hp[q];
    float d = disq[i];
    float o[H];
#pragma unroll
    for (int h = 0; h < H; ++h) {
        float s = 0.f;
#pragma unroll
        for (int k = 0; k < H; ++k) s += hv[k] * w[k*H + h];
        o[h] = s * d;
    }
    float4* yp = (float4*)(yout + (size_t)i * H);
#pragma unroll
    for (int q = 0; q < 4; ++q) yp[q] = ((float4*)o)[q];
}
__global__ void k_scatter(const int* __restrict__ src, const int* __restrict__ dst,
                          const float* __restrict__ y, float* __restrict__ acc) {
    int i = blockIdx.x * blockDim.x + threadIdx.x;
    if (i >= NE) return;
    int s = src[i], d = dst[i];
    const float4* yp = (const float4*)(y + (size_t)s * H);
    float* ap = acc + (size_t)d * H;
#pragma unroll
    for (int q = 0; q < 4; ++q) {
        float4 v = yp[q];
        atomicAdd(ap + q*4 + 0, v.x);
        atomicAdd(ap + q*4 + 1, v.y);
        atomicAdd(ap + q*4 + 2, v.z);
        atomicAdd(ap + q*4 + 3, v.w);
    }
}
__global__ void k_post(const float* __restrict__ acc, const float* __restrict__ disq,
                       const float* __restrict__ b, float* __restrict__ hout) {
    __shared__ float bs[H];
    if (threadIdx.x < H) bs[threadIdx.x] = b[threadIdx.x];
    __syncthreads();
    int i = blockIdx.x * blockDim.x + threadIdx.x;
    if (i >= NN) return;
    float d = disq[i];
    const float4* ap = (const float4*)(acc + (size_t)i * H);
    float4* hp = (float4*)(hout + (size_t)i * H);
#pragma unroll
    for (int q = 0; q < 4; ++q) {
        float4 v = ap[q];
        float4 r;
        r.x = fmaxf(v.x * d + bs[q*4+0], 0.f);
        r.y = fmaxf(v.y * d + bs[q*4+1], 0.f);
        r.z = fmaxf(v.z * d + bs[q*4+2], 0.f);
        r.w = fmaxf(v.w * d + bs[q*4+3], 0.f);
        hp[q] = r;
    }
}

extern "C" void kernel_launch(void* const* d_in, const int* in_sizes, int n_in,
                              void* d_out, int out_size, void* d_ws, size_t ws_size,
                              hipStream_t stream) {
    const float* x   = (const float*)d_in[0];
    const float* W1  = (const float*)d_in[1];
    const float* b1  = (const float*)d_in[2];
    const float* W2  = (const float*)d_in[3];
    const float* b2  = (const float*)d_in[4];
    const float* Wf1 = (const float*)d_in[5];
    const float* bf1 = (const float*)d_in[6];
    const float* Wf2 = (const float*)d_in[7];
    const float* bf2 = (const float*)d_in[8];
    const int*   ei    = (const int*)d_in[9];
    const int*   batch = (const int*)d_in[10];
    const int* src = ei;        // edge_index row 0
    const int* dst = ei + NE;   // edge_index row 1
    float* out = (float*)d_out;

    const int BT  = 256;
    const int gbN = (NN + BT - 1) / BT;               // 586
    const int gbE = (NE + BT - 1) / BT;               // 18750 (fallback)
    const int NPB = BT / H;                           // 16
    const int gbG = (NN + NPB - 1) / NPB;             // 9375 gather blocks
    const int gbP = (NG + NPB - 1) / NPB;             // 32

    // ---- workspace layout (4-byte words; region starts 16B-aligned) ----
    // mat[256*1024] | tot[1024] | base[1025]pad | ed[NE] | csr[NE] | rs[NN+1]pad |
    // disq[NN] | ybf[NN*H bf16 = 1.2M words] | bufB[NN*H f32] | g[NG*H]
    size_t need = ((size_t)13772408) * 4;   // ~55.1 MB
    if (ws_size >= need) {
        int*      mat  = (int*)d_ws;                   // 262144
        int*      tot  = mat + 262144;                 // 1024
        int*      base = mat + 263168;                 // 1025 (pad to 264208)
        unsigned* ed   = (unsigned*)(mat + 264208);    // NE
        int*      csr  = mat + 5064208;                // NE
        int*      rs   = mat + 9864208;                // NN+1 (pad to 10014216)
        float*    disq = (float*)(mat + 10014216);     // NN
        unsigned short* ybf = (unsigned short*)(mat + 10164216); // NN*H bf16
        float*    bufB = (float*)(mat + 11364216);     // NN*H
        float*    g    = (float*)(mat + 13764216);     // NG*H

        // graph bucketing + per-bucket counting sort -> CSR (no global atomics)
        k_hist  <<<NBLK, 256, 0, stream>>>(dst, mat);
        k_scanb <<<NB,   NBLK, 0, stream>>>(mat, tot);
        k_scant <<<1,    NB,  0, stream>>>(tot, base);
        k_bucket<<<NBLK, 256, 0, stream>>>(src, dst, mat, base, ed);
        k_csr   <<<NB,   256, 0, stream>>>(ed, base, rs, csr, disq);

        // conv1
        k_xw1   <<<gbN, 256, 0, stream>>>(x, W1, disq, ybf);
        k_gather<<<gbG, 256, 0, stream>>>(rs, csr, ybf, disq, b1, bufB);   // h1
        // conv2
        k_hw2   <<<gbN, 256, 0, stream>>>(bufB, W2, disq, ybf);            // y2
        k_gather<<<gbG, 256, 0, stream>>>(rs, csr, ybf, disq, b2, bufB);   // h2
        // pool + MLP
        k_pool_seg<<<gbP, 256, 0, stream>>>(bufB, batch, g);
        k_mlp<<<1, 512, 0, stream>>>(g, Wf1, bf1, Wf2, bf2, out);
    } else {
        // fallback: baseline atomic-scatter path (~20 MB ws, f32)
        float* disq = (float*)d_ws;
        float* bufA = disq + NN;
        float* bufB = bufA + (size_t)NN * H;
        float* g    = bufB + (size_t)NN * H;

        k_deg_init<<<gbN, BT, 0, stream>>>(disq);
        k_deg_edges<<<gbE, BT, 0, stream>>>(dst, disq);
        k_disq<<<gbN, BT, 0, stream>>>(disq);

        k_xw1f<<<gbN, BT, 0, stream>>>(x, W1, disq, bufA);
        hipMemcpyAsync(bufB, bufA, (size_t)NN * H * sizeof(float),
                       hipMemcpyDeviceToDevice, stream);
        k_scatter<<<gbE, BT, 0, stream>>>(src, dst, bufA, bufB);
        k_post<<<gbN, BT, 0, stream>>>(bufB, disq, b1, bufA);

        k_hw2f<<<gbN, BT, 0, stream>>>(bufA, W2, disq, bufB);
        hipMemcpyAsync(bufA, bufB, (size_t)NN * H * sizeof(float),
                       hipMemcpyDeviceToDevice, stream);
        k_scatter<<<gbE, BT, 0, stream>>>(src, dst, bufB, bufA);
        k_post<<<gbN, BT, 0, stream>>>(bufA, disq, b2, bufB);

        k_pool_seg<<<gbP, BT, 0, stream>>>(bufB, batch, g);
        k_mlp<<<1, 512, 0, stream>>>(g, Wf1, bf1, Wf2, bf2, out);
    }
}

// Round 11
// 253.580 us; speedup vs baseline: 3.9907x; 1.3480x over previous
//
#include <hip/hip_runtime.h>

constexpr int NN = 150000;   // nodes
constexpr int NE = 4800000;  // edges
constexpr int NG = 512;      // graphs
constexpr int H  = 16;       // hidden
constexpr int NB   = 1024;   // coarse dst-buckets
constexpr int NPBK = 147;    // nodes per bucket (ceil NN/NB)
constexpr int NBLK = 256;    // streaming blocks for hist/bucket
constexpr int CHUNK = (NE + NBLK - 1) / NBLK;   // 18750 edges per block

__device__ inline unsigned short f2bf(float f) {
    union { float f; unsigned u; } v; v.f = f;
    unsigned r = v.u + 0x7FFFu + ((v.u >> 16) & 1u);   // RNE
    return (unsigned short)(r >> 16);
}
__device__ inline float bf2f(unsigned short s) {
    union { unsigned u; float f; } v; v.u = ((unsigned)s) << 16;
    return v.f;
}

// ---------- phase A: per-block LDS histogram of dst buckets ----------
__global__ void k_hist(const int* __restrict__ dst, int* __restrict__ mat) {
    __shared__ int cnt[NB];
    for (int t = threadIdx.x; t < NB; t += 256) cnt[t] = 0;
    __syncthreads();
    int b = blockIdx.x;
    int e0 = b * CHUNK, e1 = min(e0 + CHUNK, NE);
    for (int e = e0 + (int)threadIdx.x; e < e1; e += 256)
        atomicAdd(&cnt[dst[e] / NPBK], 1);
    __syncthreads();
    for (int t = threadIdx.x; t < NB; t += 256) mat[b * NB + t] = cnt[t];
}

// ---------- column scan: mat[:,j] -> exclusive prefix, totals ----------
__global__ void k_scanb(int* __restrict__ mat, int* __restrict__ tot) {
    __shared__ int tmp[NBLK];
    int j = blockIdx.x, t = threadIdx.x;
    int v = mat[t * NB + j];
    tmp[t] = v;
    __syncthreads();
    for (int off = 1; off < NBLK; off <<= 1) {
        int a = (t >= off) ? tmp[t - off] : 0;
        __syncthreads();
        tmp[t] += a;
        __syncthreads();
    }
    mat[t * NB + j] = tmp[t] - v;               // exclusive within column
    if (t == NBLK - 1) tot[j] = tmp[t];
}

// ---------- bucket base scan (exclusive over 1024 buckets) ----------
__global__ void k_scant(const int* __restrict__ tot, int* __restrict__ base) {
    __shared__ int tmp[NB];
    int t = threadIdx.x;
    int v = tot[t];
    tmp[t] = v;
    __syncthreads();
    for (int off = 1; off < NB; off <<= 1) {
        int a = (t >= off) ? tmp[t - off] : 0;
        __syncthreads();
        tmp[t] += a;
        __syncthreads();
    }
    base[t] = tmp[t] - v;
    if (t == 0) base[NB] = NE;
}

// ---------- phase B: packed (src | local_dst<<18) grouped by bucket ----------
__global__ void k_bucket(const int* __restrict__ src, const int* __restrict__ dst,
                         const int* __restrict__ mat, const int* __restrict__ base,
                         unsigned* __restrict__ ed) {
    __shared__ int cur[NB];
    int b = blockIdx.x;
    for (int t = threadIdx.x; t < NB; t += 256) cur[t] = base[t] + mat[b * NB + t];
    __syncthreads();
    int e0 = b * CHUNK, e1 = min(e0 + CHUNK, NE);
    for (int e = e0 + (int)threadIdx.x; e < e1; e += 256) {
        int d = dst[e];
        int bq = d / NPBK;
        int p = atomicAdd(&cur[bq], 1);
        ed[p] = (unsigned)src[e] | ((unsigned)(d - bq * NPBK) << 18);
    }
}

// ---------- phase B2: per-bucket counting sort by local dst -> full CSR + disq ----------
__global__ void k_csr(const unsigned* __restrict__ ed, const int* __restrict__ base,
                      int* __restrict__ rs, int* __restrict__ csr,
                      float* __restrict__ disq) {
    __shared__ int cnt[256];
    __shared__ int scn[256];
    int j = blockIdx.x, t = threadIdx.x;
    cnt[t] = 0;
    __syncthreads();
    int e0 = base[j], e1 = base[j + 1];
    for (int e = e0 + t; e < e1; e += 256)
        atomicAdd(&cnt[ed[e] >> 18], 1);
    __syncthreads();
    int v = cnt[t];
    scn[t] = v;
    __syncthreads();
    for (int off = 1; off < 256; off <<= 1) {
        int a = (t >= off) ? scn[t - off] : 0;
        __syncthreads();
        scn[t] += a;
        __syncthreads();
    }
    int excl = scn[t] - v;                       // exclusive scan
    int n0 = j * NPBK;
    if (t < NPBK && n0 + t < NN) {
        rs[n0 + t] = e0 + excl;
        disq[n0 + t] = rsqrtf((float)(v + 1));   // +1 self-loop
    }
    cnt[t] = excl;                               // reuse as cursor
    __syncthreads();
    for (int e = e0 + t; e < e1; e += 256) {
        unsigned ee = ed[e];
        int p = atomicAdd(&cnt[ee >> 18], 1);
        csr[e0 + p] = (int)(ee & 0x3FFFFu);
    }
    if (j == 0 && t == 0) rs[NN] = NE;
}

// ---------- y = (x @ W1) * disq  -> bf16 ----------
__global__ void k_xw1(const float* __restrict__ x, const float* __restrict__ W1,
                      const float* __restrict__ disq, unsigned short* __restrict__ y) {
    __shared__ float w[4 * H];
    if (threadIdx.x < 4 * H) w[threadIdx.x] = W1[threadIdx.x];
    __syncthreads();
    int i = blockIdx.x * blockDim.x + threadIdx.x;
    if (i >= NN) return;
    float4 xv = ((const float4*)x)[i];
    float d = disq[i];
    float o[H];
#pragma unroll
    for (int h = 0; h < H; ++h)
        o[h] = (xv.x * w[0*H + h] + xv.y * w[1*H + h] +
                xv.z * w[2*H + h] + xv.w * w[3*H + h]) * d;
    unsigned pk[8];
#pragma unroll
    for (int q = 0; q < 8; ++q)
        pk[q] = (unsigned)f2bf(o[2*q]) | ((unsigned)f2bf(o[2*q+1]) << 16);
    uint4* yp = (uint4*)(y + (size_t)i * H);
    yp[0] = make_uint4(pk[0], pk[1], pk[2], pk[3]);
    yp[1] = make_uint4(pk[4], pk[5], pk[6], pk[7]);
}

// ---------- gather: 16 lanes/node, 8-way unrolled for MLP ----------
// h[n] = relu(disq[n] * (y[n] + sum y[csr]) + b)
__global__ void k_gather(const int* __restrict__ rs, const int* __restrict__ csr,
                         const unsigned short* __restrict__ y, const float* __restrict__ disq,
                         const float* __restrict__ b, float* __restrict__ hout) {
    int n    = blockIdx.x * 16 + (threadIdx.x >> 4);
    int lane = threadIdx.x & 15;
    if (n >= NN) return;
    int s0 = rs[n], s1 = rs[n + 1];
    float acc = bf2f(y[(size_t)n * H + lane]);   // self-loop term
    int k = s0;
    for (; k + 8 <= s1; k += 8) {
        int sa = csr[k+0], sb = csr[k+1], sc = csr[k+2], sd = csr[k+3];
        int se = csr[k+4], sf = csr[k+5], sg = csr[k+6], sh = csr[k+7];
        float v0 = bf2f(y[(size_t)sa * H + lane]);
        float v1 = bf2f(y[(size_t)sb * H + lane]);
        float v2 = bf2f(y[(size_t)sc * H + lane]);
        float v3 = bf2f(y[(size_t)sd * H + lane]);
        float v4 = bf2f(y[(size_t)se * H + lane]);
        float v5 = bf2f(y[(size_t)sf * H + lane]);
        float v6 = bf2f(y[(size_t)sg * H + lane]);
        float v7 = bf2f(y[(size_t)sh * H + lane]);
        acc += ((v0 + v1) + (v2 + v3)) + ((v4 + v5) + (v6 + v7));
    }
    for (; k < s1; ++k) acc += bf2f(y[(size_t)csr[k] * H + lane]);
    hout[(size_t)n * H + lane] = fmaxf(fmaf(acc, disq[n], b[lane]), 0.f);
}

// ---------- y = (h @ W2) * disq -> bf16 ----------
__global__ void k_hw2(const float* __restrict__ hin, const float* __restrict__ W2,
                      const float* __restrict__ disq, unsigned short* __restrict__ yout) {
    __shared__ float w[H * H];
    if (threadIdx.x < H * H) w[threadIdx.x] = W2[threadIdx.x];
    __syncthreads();
    int i = blockIdx.x * blockDim.x + threadIdx.x;
    if (i >= NN) return;
    float hv[H];
    const float4* hp = (const float4*)(hin + (size_t)i * H);
#pragma unroll
    for (int q = 0; q < 4; ++q) ((float4*)hv)[q] = hp[q];
    float d = disq[i];
    float o[H];
#pragma unroll
    for (int h = 0; h < H; ++h) {
        float s = 0.f;
#pragma unroll
        for (int k = 0; k < H; ++k) s += hv[k] * w[k*H + h];
        o[h] = s * d;
    }
    unsigned pk[8];
#pragma unroll
    for (int q = 0; q < 8; ++q)
        pk[q] = (unsigned)f2bf(o[2*q]) | ((unsigned)f2bf(o[2*q+1]) << 16);
    uint4* yp = (uint4*)(yout + (size_t)i * H);
    yp[0] = make_uint4(pk[0], pk[1], pk[2], pk[3]);
    yp[1] = make_uint4(pk[4], pk[5], pk[6], pk[7]);
}

// ---------- pool v2: one block per graph, 16 groups x 16 lanes + LDS tree ----------
__global__ void k_pool_blk(const float* __restrict__ h, const int* __restrict__ batch,
                           float* __restrict__ gout) {
    __shared__ float red[16][H + 1];
    int g    = blockIdx.x;
    int lane = threadIdx.x & 15;
    int grp  = threadIdx.x >> 4;                 // 0..15
    // segment bounds via binary search (batch sorted ascending)
    int lo = 0, hi = NN;
    while (lo < hi) { int m = (lo + hi) >> 1; if (batch[m] < g) lo = m + 1; else hi = m; }
    int start = lo;
    hi = NN;
    while (lo < hi) { int m = (lo + hi) >> 1; if (batch[m] < g + 1) lo = m + 1; else hi = m; }
    int end = lo;
    float acc = 0.f;
    for (int i = start + grp; i < end; i += 16)
        acc += h[(size_t)i * H + lane];
    red[grp][lane] = acc;
    __syncthreads();
    if (grp < 8) red[grp][lane] += red[grp + 8][lane];
    __syncthreads();
    if (grp < 4) red[grp][lane] += red[grp + 4][lane];
    __syncthreads();
    if (grp < 2) red[grp][lane] += red[grp + 2][lane];
    __syncthreads();
    if (grp == 0)
        gout[(size_t)g * H + lane] = red[0][lane] + red[1][lane];
}

// ---------- final MLP ----------
__global__ void k_mlp(const float* __restrict__ g, const float* __restrict__ Wf1,
                      const float* __restrict__ bf1, const float* __restrict__ Wf2,
                      const float* __restrict__ bf2, float* __restrict__ out) {
    __shared__ float w1[H * H];
    __shared__ float b1s[H];
    __shared__ float w2[H];
    __shared__ float b2s;
    if (threadIdx.x < H * H) w1[threadIdx.x] = Wf1[threadIdx.x];
    if (threadIdx.x < H) { b1s[threadIdx.x] = bf1[threadIdx.x]; w2[threadIdx.x] = Wf2[threadIdx.x]; }
    if (threadIdx.x == 0) b2s = bf2[0];
    __syncthreads();
    int i = blockIdx.x * blockDim.x + threadIdx.x;
    if (i >= NG) return;
    float gv[H];
    const float4* gp = (const float4*)(g + (size_t)i * H);
#pragma unroll
    for (int q = 0; q < 4; ++q) ((float4*)gv)[q] = gp[q];
    float s2 = 0.f;
#pragma unroll
    for (int h = 0; h < H; ++h) {
        float t = b1s[h];
#pragma unroll
        for (int k = 0; k < H; ++k) t += gv[k] * w1[k*H + h];
        s2 += fmaxf(t, 0.f) * w2[h];
    }
    out[i] = s2 + b2s;
}

// ================= fallback (baseline atomic path, f32) =================
__global__ void k_deg_init(float* __restrict__ deg) {
    int i = blockIdx.x * blockDim.x + threadIdx.x;
    if (i < NN) deg[i] = 1.0f;
}
__global__ void k_deg_edges(const int* __restrict__ dst, float* __restrict__ deg) {
    int i = blockIdx.x * blockDim.x + threadIdx.x;
    if (i < NE) atomicAdd(&deg[dst[i]], 1.0f);
}
__global__ void k_disq(float* __restrict__ deg) {
    int i = blockIdx.x * blockDim.x + threadIdx.x;
    if (i < NN) deg[i] = rsqrtf(deg[i]);
}
__global__ void k_xw1f(const float* __restrict__ x, const float* __restrict__ W1,
                       const float* __restrict__ disq, float* __restrict__ y) {
    __shared__ float w[4 * H];
    if (threadIdx.x < 4 * H) w[threadIdx.x] = W1[threadIdx.x];
    __syncthreads();
    int i = blockIdx.x * blockDim.x + threadIdx.x;
    if (i >= NN) return;
    float4 xv = ((const float4*)x)[i];
    float d = disq[i];
    float o[H];
#pragma unroll
    for (int h = 0; h < H; ++h)
        o[h] = (xv.x * w[0*H + h] + xv.y * w[1*H + h] +
                xv.z * w[2*H + h] + xv.w * w[3*H + h]) * d;
    float4* yp = (float4*)(y + (size_t)i * H);
#pragma unroll
    for (int q = 0; q < 4; ++q) yp[q] = ((float4*)o)[q];
}
__global__ void k_hw2f(const float* __restrict__ hin, const float* __restrict__ W2,
                       const float* __restrict__ disq, float* __restrict__ yout) {
    __shared__ float w[H * H];
    if (threadIdx.x < H * H) w[threadIdx.x] = W2[threadIdx.x];
    __syncthreads();
    int i = blockIdx.x * blockDim.x + threadIdx.x;
    if (i >= NN) return;
    float hv[H];
    const float4* hp = (const float4*)(hin + (size_t)i * H);
#pragma unroll
    for (int q = 0; q < 4; ++q) ((float4*)hv)[q] = hp[q];
    float d = disq[i];
    float o[H];
#pragma unroll
    for (int h = 0; h < H; ++h) {
        float s = 0.f;
#pragma unroll
        for (int k = 0; k < H; ++k) s += hv[k] * w[k*H + h];
        o[h] = s * d;
    }
    float4* yp = (float4*)(yout + (size_t)i * H);
#pragma unroll
    for (int q = 0; q < 4; ++q) yp[q] = ((float4*)o)[q];
}
__global__ void k_scatter(const int* __restrict__ src, const int* __restrict__ dst,
                          const float* __restrict__ y, float* __restrict__ acc) {
    int i = blockIdx.x * blockDim.x + threadIdx.x;
    if (i >= NE) return;
    int s = src[i], d = dst[i];
    const float4* yp = (const float4*)(y + (size_t)s * H);
    float* ap = acc + (size_t)d * H;
#pragma unroll
    for (int q = 0; q < 4; ++q) {
        float4 v = yp[q];
        atomicAdd(ap + q*4 + 0, v.x);
        atomicAdd(ap + q*4 + 1, v.y);
        atomicAdd(ap + q*4 + 2, v.z);
        atomicAdd(ap + q*4 + 3, v.w);
    }
}
__global__ void k_post(const float* __restrict__ acc, const float* __restrict__ disq,
                       const float* __restrict__ b, float* __restrict__ hout) {
    __shared__ float bs[H];
    if (threadIdx.x < H) bs[threadIdx.x] = b[threadIdx.x];
    __syncthreads();
    int i = blockIdx.x * blockDim.x + threadIdx.x;
    if (i >= NN) return;
    float d = disq[i];
    const float4* ap = (const float4*)(acc + (size_t)i * H);
    float4* hp = (float4*)(hout + (size_t)i * H);
#pragma unroll
    for (int q = 0; q < 4; ++q) {
        float4 v = ap[q];
        float4 r;
        r.x = fmaxf(v.x * d + bs[q*4+0], 0.f);
        r.y = fmaxf(v.y * d + bs[q*4+1], 0.f);
        r.z = fmaxf(v.z * d + bs[q*4+2], 0.f);
        r.w = fmaxf(v.w * d + bs[q*4+3], 0.f);
        hp[q] = r;
    }
}

extern "C" void kernel_launch(void* const* d_in, const int* in_sizes, int n_in,
                              void* d_out, int out_size, void* d_ws, size_t ws_size,
                              hipStream_t stream) {
    const float* x   = (const float*)d_in[0];
    const float* W1  = (const float*)d_in[1];
    const float* b1  = (const float*)d_in[2];
    const float* W2  = (const float*)d_in[3];
    const float* b2  = (const float*)d_in[4];
    const float* Wf1 = (const float*)d_in[5];
    const float* bf1 = (const float*)d_in[6];
    const float* Wf2 = (const float*)d_in[7];
    const float* bf2 = (const float*)d_in[8];
    const int*   ei    = (const int*)d_in[9];
    const int*   batch = (const int*)d_in[10];
    const int* src = ei;        // edge_index row 0
    const int* dst = ei + NE;   // edge_index row 1
    float* out = (float*)d_out;

    const int BT  = 256;
    const int gbN = (NN + BT - 1) / BT;               // 586
    const int gbE = (NE + BT - 1) / BT;               // 18750 (fallback)
    const int NPB = BT / H;                           // 16
    const int gbG = (NN + NPB - 1) / NPB;             // 9375 gather blocks

    // ---- workspace layout (4-byte words; region starts 16B-aligned) ----
    // mat[256*1024] | tot[1024] | base[1025]pad | ed[NE] | csr[NE] | rs[NN+1]pad |
    // disq[NN] | ybf[NN*H bf16 = 1.2M words] | bufB[NN*H f32] | g[NG*H]
    size_t need = ((size_t)13772408) * 4;   // ~55.1 MB
    if (ws_size >= need) {
        int*      mat  = (int*)d_ws;                   // 262144
        int*      tot  = mat + 262144;                 // 1024
        int*      base = mat + 263168;                 // 1025 (pad to 264208)
        unsigned* ed   = (unsigned*)(mat + 264208);    // NE
        int*      csr  = mat + 5064208;                // NE
        int*      rs   = mat + 9864208;                // NN+1 (pad to 10014216)
        float*    disq = (float*)(mat + 10014216);     // NN
        unsigned short* ybf = (unsigned short*)(mat + 10164216); // NN*H bf16
        float*    bufB = (float*)(mat + 11364216);     // NN*H
        float*    g    = (float*)(mat + 13764216);     // NG*H

        // graph bucketing + per-bucket counting sort -> CSR (no global atomics)
        k_hist  <<<NBLK, 256, 0, stream>>>(dst, mat);
        k_scanb <<<NB,   NBLK, 0, stream>>>(mat, tot);
        k_scant <<<1,    NB,  0, stream>>>(tot, base);
        k_bucket<<<NBLK, 256, 0, stream>>>(src, dst, mat, base, ed);
        k_csr   <<<NB,   256, 0, stream>>>(ed, base, rs, csr, disq);

        // conv1
        k_xw1   <<<gbN, 256, 0, stream>>>(x, W1, disq, ybf);
        k_gather<<<gbG, 256, 0, stream>>>(rs, csr, ybf, disq, b1, bufB);   // h1
        // conv2
        k_hw2   <<<gbN, 256, 0, stream>>>(bufB, W2, disq, ybf);            // y2
        k_gather<<<gbG, 256, 0, stream>>>(rs, csr, ybf, disq, b2, bufB);   // h2
        // pool + MLP
        k_pool_blk<<<NG, 256, 0, stream>>>(bufB, batch, g);
        k_mlp<<<1, 512, 0, stream>>>(g, Wf1, bf1, Wf2, bf2, out);
    } else {
        // fallback: baseline atomic-scatter path (~20 MB ws, f32)
        float* disq = (float*)d_ws;
        float* bufA = disq + NN;
        float* bufB = bufA + (size_t)NN * H;
        float* g    = bufB + (size_t)NN * H;

        k_deg_init<<<gbN, BT, 0, stream>>>(disq);
        k_deg_edges<<<gbE, BT, 0, stream>>>(dst, disq);
        k_disq<<<gbN, BT, 0, stream>>>(disq);

        k_xw1f<<<gbN, BT, 0, stream>>>(x, W1, disq, bufA);
        hipMemcpyAsync(bufB, bufA, (size_t)NN * H * sizeof(float),
                       hipMemcpyDeviceToDevice, stream);
        k_scatter<<<gbE, BT, 0, stream>>>(src, dst, bufA, bufB);
        k_post<<<gbN, BT, 0, stream>>>(bufB, disq, b1, bufA);

        k_hw2f<<<gbN, BT, 0, stream>>>(bufA, W2, disq, bufB);
        hipMemcpyAsync(bufA, bufB, (size_t)NN * H * sizeof(float),
                       hipMemcpyDeviceToDevice, stream);
        k_scatter<<<gbE, BT, 0, stream>>>(src, dst, bufB, bufA);
        k_post<<<gbN, BT, 0, stream>>>(bufA, disq, b2, bufB);

        k_pool_blk<<<NG, BT, 0, stream>>>(bufB, batch, g);
        k_mlp<<<1, 512, 0, stream>>>(g, Wf1, bf1, Wf2, bf2, out);
    }
}

// Round 12
// 251.881 us; speedup vs baseline: 4.0176x; 1.0067x over previous
//
#include <hip/hip_runtime.h>

constexpr int NN = 150000;   // nodes
constexpr int NE = 4800000;  // edges
constexpr int NG = 512;      // graphs
constexpr int H  = 16;       // hidden
constexpr int NB   = 512;    // coarse dst-buckets
constexpr int NPBK = 293;    // nodes per bucket (ceil NN/NB)
constexpr int NBLK = 256;    // streaming blocks for hist/bucket
constexpr int CHUNK = (NE + NBLK - 1) / NBLK;   // 18750 edges per block

__device__ inline unsigned short f2bf(float f) {
    union { float f; unsigned u; } v; v.f = f;
    unsigned r = v.u + 0x7FFFu + ((v.u >> 16) & 1u);   // RNE
    return (unsigned short)(r >> 16);
}
__device__ inline float bf2f(unsigned short s) {
    union { unsigned u; float f; } v; v.u = ((unsigned)s) << 16;
    return v.f;
}

// ---------- phase A: per-block LDS histogram of dst buckets ----------
__global__ void k_hist(const int* __restrict__ dst, int* __restrict__ mat) {
    __shared__ int cnt[NB];
    for (int t = threadIdx.x; t < NB; t += 256) cnt[t] = 0;
    __syncthreads();
    int b = blockIdx.x;
    int e0 = b * CHUNK, e1 = min(e0 + CHUNK, NE);
    for (int e = e0 + (int)threadIdx.x; e < e1; e += 256)
        atomicAdd(&cnt[dst[e] / NPBK], 1);
    __syncthreads();
    for (int t = threadIdx.x; t < NB; t += 256) mat[b * NB + t] = cnt[t];
}

// ---------- column scan: mat[:,j] -> exclusive prefix, totals ----------
__global__ void k_scanb(int* __restrict__ mat, int* __restrict__ tot) {
    __shared__ int tmp[NBLK];
    int j = blockIdx.x, t = threadIdx.x;
    int v = mat[t * NB + j];
    tmp[t] = v;
    __syncthreads();
    for (int off = 1; off < NBLK; off <<= 1) {
        int a = (t >= off) ? tmp[t - off] : 0;
        __syncthreads();
        tmp[t] += a;
        __syncthreads();
    }
    mat[t * NB + j] = tmp[t] - v;               // exclusive within column
    if (t == NBLK - 1) tot[j] = tmp[t];
}

// ---------- bucket base scan (exclusive over NB buckets) ----------
__global__ void k_scant(const int* __restrict__ tot, int* __restrict__ base) {
    __shared__ int tmp[NB];
    int t = threadIdx.x;
    int v = tot[t];
    tmp[t] = v;
    __syncthreads();
    for (int off = 1; off < NB; off <<= 1) {
        int a = (t >= off) ? tmp[t - off] : 0;
        __syncthreads();
        tmp[t] += a;
        __syncthreads();
    }
    base[t] = tmp[t] - v;
    if (t == 0) base[NB] = NE;
}

// ---------- phase B: packed (src | local_dst<<18) grouped by bucket ----------
__global__ void k_bucket(const int* __restrict__ src, const int* __restrict__ dst,
                         const int* __restrict__ mat, const int* __restrict__ base,
                         unsigned* __restrict__ ed) {
    __shared__ int cur[NB];
    int b = blockIdx.x;
    for (int t = threadIdx.x; t < NB; t += 256) cur[t] = base[t] + mat[b * NB + t];
    __syncthreads();
    int e0 = b * CHUNK, e1 = min(e0 + CHUNK, NE);
    for (int e = e0 + (int)threadIdx.x; e < e1; e += 256) {
        int d = dst[e];
        int bq = d / NPBK;
        int p = atomicAdd(&cur[bq], 1);
        ed[p] = (unsigned)src[e] | ((unsigned)(d - bq * NPBK) << 18);
    }
}

// ---------- phase B2: per-bucket counting sort (NPBK=293) -> CSR + disq ----------
__global__ void k_csr(const unsigned* __restrict__ ed, const int* __restrict__ base,
                      int* __restrict__ rs, int* __restrict__ csr,
                      float* __restrict__ disq) {
    __shared__ int cnt[2 * 256];     // 512 slots >= NPBK, counters then cursors
    __shared__ int exc[2 * 256];     // exclusive prefix per slot
    __shared__ int scn[256];
    int j = blockIdx.x, t = threadIdx.x;
    cnt[t] = 0; cnt[t + 256] = 0;
    __syncthreads();
    int e0 = base[j], e1 = base[j + 1];
    for (int e = e0 + t; e < e1; e += 256)
        atomicAdd(&cnt[ed[e] >> 18], 1);
    __syncthreads();
    // exclusive scan over 512 slots: 2 elems/thread + Hillis-Steele + add-back
    int a0 = cnt[2 * t], a1 = cnt[2 * t + 1];
    int s = a0 + a1;
    scn[t] = s;
    __syncthreads();
    for (int off = 1; off < 256; off <<= 1) {
        int a = (t >= off) ? scn[t - off] : 0;
        __syncthreads();
        scn[t] += a;
        __syncthreads();
    }
    int eth = scn[t] - s;                        // exclusive thread offset
    exc[2 * t] = eth;
    exc[2 * t + 1] = eth + a0;
    __syncthreads();
    int n0 = j * NPBK;
    for (int q = t; q < NPBK; q += 256) {
        int n = n0 + q;
        if (n < NN) {
            rs[n] = e0 + exc[q];
            disq[n] = rsqrtf((float)(cnt[q] + 1));   // +1 self-loop
        }
    }
    // cursors = exclusive offsets
    cnt[t] = exc[t]; cnt[t + 256] = exc[t + 256];
    __syncthreads();
    for (int e = e0 + t; e < e1; e += 256) {
        unsigned ee = ed[e];
        int p = atomicAdd(&cnt[ee >> 18], 1);
        csr[e0 + p] = (int)(ee & 0x3FFFFu);
    }
    if (j == 0 && t == 0) rs[NN] = NE;
}

// ---------- y = (x @ W1) * disq  -> bf16 ----------
__global__ void k_xw1(const float* __restrict__ x, const float* __restrict__ W1,
                      const float* __restrict__ disq, unsigned short* __restrict__ y) {
    __shared__ float w[4 * H];
    if (threadIdx.x < 4 * H) w[threadIdx.x] = W1[threadIdx.x];
    __syncthreads();
    int i = blockIdx.x * blockDim.x + threadIdx.x;
    if (i >= NN) return;
    float4 xv = ((const float4*)x)[i];
    float d = disq[i];
    float o[H];
#pragma unroll
    for (int h = 0; h < H; ++h)
        o[h] = (xv.x * w[0*H + h] + xv.y * w[1*H + h] +
                xv.z * w[2*H + h] + xv.w * w[3*H + h]) * d;
    unsigned pk[8];
#pragma unroll
    for (int q = 0; q < 8; ++q)
        pk[q] = (unsigned)f2bf(o[2*q]) | ((unsigned)f2bf(o[2*q+1]) << 16);
    uint4* yp = (uint4*)(y + (size_t)i * H);
    yp[0] = make_uint4(pk[0], pk[1], pk[2], pk[3]);
    yp[1] = make_uint4(pk[4], pk[5], pk[6], pk[7]);
}

// ---------- gather: 16 lanes/node, 8-way unrolled for MLP ----------
__global__ void k_gather(const int* __restrict__ rs, const int* __restrict__ csr,
                         const unsigned short* __restrict__ y, const float* __restrict__ disq,
                         const float* __restrict__ b, float* __restrict__ hout) {
    int n    = blockIdx.x * 16 + (threadIdx.x >> 4);
    int lane = threadIdx.x & 15;
    if (n >= NN) return;
    int s0 = rs[n], s1 = rs[n + 1];
    float acc = bf2f(y[(size_t)n * H + lane]);   // self-loop term
    int k = s0;
    for (; k + 8 <= s1; k += 8) {
        int sa = csr[k+0], sb = csr[k+1], sc = csr[k+2], sd = csr[k+3];
        int se = csr[k+4], sf = csr[k+5], sg = csr[k+6], sh = csr[k+7];
        float v0 = bf2f(y[(size_t)sa * H + lane]);
        float v1 = bf2f(y[(size_t)sb * H + lane]);
        float v2 = bf2f(y[(size_t)sc * H + lane]);
        float v3 = bf2f(y[(size_t)sd * H + lane]);
        float v4 = bf2f(y[(size_t)se * H + lane]);
        float v5 = bf2f(y[(size_t)sf * H + lane]);
        float v6 = bf2f(y[(size_t)sg * H + lane]);
        float v7 = bf2f(y[(size_t)sh * H + lane]);
        acc += ((v0 + v1) + (v2 + v3)) + ((v4 + v5) + (v6 + v7));
    }
    for (; k < s1; ++k) acc += bf2f(y[(size_t)csr[k] * H + lane]);
    hout[(size_t)n * H + lane] = fmaxf(fmaf(acc, disq[n], b[lane]), 0.f);
}

// ---------- y = (h @ W2) * disq -> bf16 ----------
__global__ void k_hw2(const float* __restrict__ hin, const float* __restrict__ W2,
                      const float* __restrict__ disq, unsigned short* __restrict__ yout) {
    __shared__ float w[H * H];
    if (threadIdx.x < H * H) w[threadIdx.x] = W2[threadIdx.x];
    __syncthreads();
    int i = blockIdx.x * blockDim.x + threadIdx.x;
    if (i >= NN) return;
    float hv[H];
    const float4* hp = (const float4*)(hin + (size_t)i * H);
#pragma unroll
    for (int q = 0; q < 4; ++q) ((float4*)hv)[q] = hp[q];
    float d = disq[i];
    float o[H];
#pragma unroll
    for (int h = 0; h < H; ++h) {
        float s = 0.f;
#pragma unroll
        for (int k = 0; k < H; ++k) s += hv[k] * w[k*H + h];
        o[h] = s * d;
    }
    unsigned pk[8];
#pragma unroll
    for (int q = 0; q < 8; ++q)
        pk[q] = (unsigned)f2bf(o[2*q]) | ((unsigned)f2bf(o[2*q+1]) << 16);
    uint4* yp = (uint4*)(yout + (size_t)i * H);
    yp[0] = make_uint4(pk[0], pk[1], pk[2], pk[3]);
    yp[1] = make_uint4(pk[4], pk[5], pk[6], pk[7]);
}

// ---------- pool: one block per graph, 16 groups x 16 lanes + LDS tree ----------
__global__ void k_pool_blk(const float* __restrict__ h, const int* __restrict__ batch,
                           float* __restrict__ gout) {
    __shared__ float red[16][H + 1];
    int g    = blockIdx.x;
    int lane = threadIdx.x & 15;
    int grp  = threadIdx.x >> 4;                 // 0..15
    int lo = 0, hi = NN;
    while (lo < hi) { int m = (lo + hi) >> 1; if (batch[m] < g) lo = m + 1; else hi = m; }
    int start = lo;
    hi = NN;
    while (lo < hi) { int m = (lo + hi) >> 1; if (batch[m] < g + 1) lo = m + 1; else hi = m; }
    int end = lo;
    float acc = 0.f;
    for (int i = start + grp; i < end; i += 16)
        acc += h[(size_t)i * H + lane];
    red[grp][lane] = acc;
    __syncthreads();
    if (grp < 8) red[grp][lane] += red[grp + 8][lane];
    __syncthreads();
    if (grp < 4) red[grp][lane] += red[grp + 4][lane];
    __syncthreads();
    if (grp < 2) red[grp][lane] += red[grp + 2][lane];
    __syncthreads();
    if (grp == 0)
        gout[(size_t)g * H + lane] = red[0][lane] + red[1][lane];
}

// ---------- final MLP ----------
__global__ void k_mlp(const float* __restrict__ g, const float* __restrict__ Wf1,
                      const float* __restrict__ bf1, const float* __restrict__ Wf2,
                      const float* __restrict__ bf2, float* __restrict__ out) {
    __shared__ float w1[H * H];
    __shared__ float b1s[H];
    __shared__ float w2[H];
    __shared__ float b2s;
    if (threadIdx.x < H * H) w1[threadIdx.x] = Wf1[threadIdx.x];
    if (threadIdx.x < H) { b1s[threadIdx.x] = bf1[threadIdx.x]; w2[threadIdx.x] = Wf2[threadIdx.x]; }
    if (threadIdx.x == 0) b2s = bf2[0];
    __syncthreads();
    int i = blockIdx.x * blockDim.x + threadIdx.x;
    if (i >= NG) return;
    float gv[H];
    const float4* gp = (const float4*)(g + (size_t)i * H);
#pragma unroll
    for (int q = 0; q < 4; ++q) ((float4*)gv)[q] = gp[q];
    float s2 = 0.f;
#pragma unroll
    for (int h = 0; h < H; ++h) {
        float t = b1s[h];
#pragma unroll
        for (int k = 0; k < H; ++k) t += gv[k] * w1[k*H + h];
        s2 += fmaxf(t, 0.f) * w2[h];
    }
    out[i] = s2 + b2s;
}

// ================= fallback (baseline atomic path, f32) =================
__global__ void k_deg_init(float* __restrict__ deg) {
    int i = blockIdx.x * blockDim.x + threadIdx.x;
    if (i < NN) deg[i] = 1.0f;
}
__global__ void k_deg_edges(const int* __restrict__ dst, float* __restrict__ deg) {
    int i = blockIdx.x * blockDim.x + threadIdx.x;
    if (i < NE) atomicAdd(&deg[dst[i]], 1.0f);
}
__global__ void k_disq(float* __restrict__ deg) {
    int i = blockIdx.x * blockDim.x + threadIdx.x;
    if (i < NN) deg[i] = rsqrtf(deg[i]);
}
__global__ void k_xw1f(const float* __restrict__ x, const float* __restrict__ W1,
                       const float* __restrict__ disq, float* __restrict__ y) {
    __shared__ float w[4 * H];
    if (threadIdx.x < 4 * H) w[threadIdx.x] = W1[threadIdx.x];
    __syncthreads();
    int i = blockIdx.x * blockDim.x + threadIdx.x;
    if (i >= NN) return;
    float4 xv = ((const float4*)x)[i];
    float d = disq[i];
    float o[H];
#pragma unroll
    for (int h = 0; h < H; ++h)
        o[h] = (xv.x * w[0*H + h] + xv.y * w[1*H + h] +
                xv.z * w[2*H + h] + xv.w * w[3*H + h]) * d;
    float4* yp = (float4*)(y + (size_t)i * H);
#pragma unroll
    for (int q = 0; q < 4; ++q) yp[q] = ((float4*)o)[q];
}
__global__ void k_hw2f(const float* __restrict__ hin, const float* __restrict__ W2,
                       const float* __restrict__ disq, float* __restrict__ yout) {
    __shared__ float w[H * H];
    if (threadIdx.x < H * H) w[threadIdx.x] = W2[threadIdx.x];
    __syncthreads();
    int i = blockIdx.x * blockDim.x + threadIdx.x;
    if (i >= NN) return;
    float hv[H];
    const float4* hp = (const float4*)(hin + (size_t)i * H);
#pragma unroll
    for (int q = 0; q < 4; ++q) ((float4*)hv)[q] = hp[q];
    float d = disq[i];
    float o[H];
#pragma unroll
    for (int h = 0; h < H; ++h) {
        float s = 0.f;
#pragma unroll
        for (int k = 0; k < H; ++k) s += hv[k] * w[k*H + h];
        o[h] = s * d;
    }
    float4* yp = (float4*)(yout + (size_t)i * H);
#pragma unroll
    for (int q = 0; q < 4; ++q) yp[q] = ((float4*)o)[q];
}
__global__ void k_scatter(const int* __restrict__ src, const int* __restrict__ dst,
                          const float* __restrict__ y, float* __restrict__ acc) {
    int i = blockIdx.x * blockDim.x + threadIdx.x;
    if (i >= NE) return;
    int s = src[i], d = dst[i];
    const float4* yp = (const float4*)(y + (size_t)s * H);
    float* ap = acc + (size_t)d * H;
#pragma unroll
    for (int q = 0; q < 4; ++q) {
        float4 v = yp[q];
        atomicAdd(ap + q*4 + 0, v.x);
        atomicAdd(ap + q*4 + 1, v.y);
        atomicAdd(ap + q*4 + 2, v.z);
        atomicAdd(ap + q*4 + 3, v.w);
    }
}
__global__ void k_post(const float* __restrict__ acc, const float* __restrict__ disq,
                       const float* __restrict__ b, float* __restrict__ hout) {
    __shared__ float bs[H];
    if (threadIdx.x < H) bs[threadIdx.x] = b[threadIdx.x];
    __syncthreads();
    int i = blockIdx.x * blockDim.x + threadIdx.x;
    if (i >= NN) return;
    float d = disq[i];
    const float4* ap = (const float4*)(acc + (size_t)i * H);
    float4* hp = (float4*)(hout + (size_t)i * H);
#pragma unroll
    for (int q = 0; q < 4; ++q) {
        float4 v = ap[q];
        float4 r;
        r.x = fmaxf(v.x * d + bs[q*4+0], 0.f);
        r.y = fmaxf(v.y * d + bs[q*4+1], 0.f);
        r.z = fmaxf(v.z * d + bs[q*4+2], 0.f);
        r.w = fmaxf(v.w * d + bs[q*4+3], 0.f);
        hp[q] = r;
    }
}

extern "C" void kernel_launch(void* const* d_in, const int* in_sizes, int n_in,
                              void* d_out, int out_size, void* d_ws, size_t ws_size,
                              hipStream_t stream) {
    const float* x   = (const float*)d_in[0];
    const float* W1  = (const float*)d_in[1];
    const float* b1  = (const float*)d_in[2];
    const float* W2  = (const float*)d_in[3];
    const float* b2  = (const float*)d_in[4];
    const float* Wf1 = (const float*)d_in[5];
    const float* bf1 = (const float*)d_in[6];
    const float* Wf2 = (const float*)d_in[7];
    const float* bf2 = (const float*)d_in[8];
    const int*   ei    = (const int*)d_in[9];
    const int*   batch = (const int*)d_in[10];
    const int* src = ei;        // edge_index row 0
    const int* dst = ei + NE;   // edge_index row 1
    float* out = (float*)d_out;

    const int BT  = 256;
    const int gbN = (NN + BT - 1) / BT;               // 586
    const int gbE = (NE + BT - 1) / BT;               // 18750 (fallback)
    const int NPB = BT / H;                           // 16
    const int gbG = (NN + NPB - 1) / NPB;             // 9375 gather blocks

    // ---- workspace layout (4-byte words; region starts 16B-aligned) ----
    // mat[256*512] | tot[512] | base[513]pad | ed[NE] | csr[NE] | rs[NN+1]pad |
    // disq[NN] | ybf[NN*H bf16] | bufB[NN*H f32] | g[NG*H]
    size_t need = ((size_t)13640320) * 4;   // ~54.6 MB
    if (ws_size >= need) {
        int*      mat  = (int*)d_ws;                   // 131072
        int*      tot  = mat + 131072;                 // 512
        int*      base = mat + 131584;                 // 513 (pad to 132112)
        unsigned* ed   = (unsigned*)(mat + 132112);    // NE
        int*      csr  = mat + 4932112;                // NE
        int*      rs   = mat + 9732112;                // NN+1 (pad to 9882128)
        float*    disq = (float*)(mat + 9882128);      // NN
        unsigned short* ybf = (unsigned short*)(mat + 10032128); // NN*H bf16
        float*    bufB = (float*)(mat + 11232128);     // NN*H
        float*    g    = (float*)(mat + 13632128);     // NG*H

        // graph bucketing + per-bucket counting sort -> CSR (no global atomics)
        k_hist  <<<NBLK, 256, 0, stream>>>(dst, mat);
        k_scanb <<<NB,   NBLK, 0, stream>>>(mat, tot);
        k_scant <<<1,    NB,  0, stream>>>(tot, base);
        k_bucket<<<NBLK, 256, 0, stream>>>(src, dst, mat, base, ed);
        k_csr   <<<NB,   256, 0, stream>>>(ed, base, rs, csr, disq);

        // conv1
        k_xw1   <<<gbN, 256, 0, stream>>>(x, W1, disq, ybf);
        k_gather<<<gbG, 256, 0, stream>>>(rs, csr, ybf, disq, b1, bufB);   // h1
        // conv2
        k_hw2   <<<gbN, 256, 0, stream>>>(bufB, W2, disq, ybf);            // y2
        k_gather<<<gbG, 256, 0, stream>>>(rs, csr, ybf, disq, b2, bufB);   // h2
        // pool + MLP
        k_pool_blk<<<NG, 256, 0, stream>>>(bufB, batch, g);
        k_mlp<<<1, 512, 0, stream>>>(g, Wf1, bf1, Wf2, bf2, out);
    } else {
        // fallback: baseline atomic-scatter path (~20 MB ws, f32)
        float* disq = (float*)d_ws;
        float* bufA = disq + NN;
        float* bufB = bufA + (size_t)NN * H;
        float* g    = bufB + (size_t)NN * H;

        k_deg_init<<<gbN, BT, 0, stream>>>(disq);
        k_deg_edges<<<gbE, BT, 0, stream>>>(dst, disq);
        k_disq<<<gbN, BT, 0, stream>>>(disq);

        k_xw1f<<<gbN, BT, 0, stream>>>(x, W1, disq, bufA);
        hipMemcpyAsync(bufB, bufA, (size_t)NN * H * sizeof(float),
                       hipMemcpyDeviceToDevice, stream);
        k_scatter<<<gbE, BT, 0, stream>>>(src, dst, bufA, bufB);
        k_post<<<gbN, BT, 0, stream>>>(bufB, disq, b1, bufA);

        k_hw2f<<<gbN, BT, 0, stream>>>(bufA, W2, disq, bufB);
        hipMemcpyAsync(bufA, bufB, (size_t)NN * H * sizeof(float),
                       hipMemcpyDeviceToDevice, stream);
        k_scatter<<<gbE, BT, 0, stream>>>(src, dst, bufB, bufA);
        k_post<<<gbN, BT, 0, stream>>>(bufA, disq, b2, bufB);

        k_pool_blk<<<NG, BT, 0, stream>>>(bufB, batch, g);
        k_mlp<<<1, 512, 0, stream>>>(g, Wf1, bf1, Wf2, bf2, out);
    }
}

// Round 13
// 241.328 us; speedup vs baseline: 4.1933x; 1.0437x over previous
//
#include <hip/hip_runtime.h>

constexpr int NN = 150000;   // nodes
constexpr int NE = 4800000;  // edges
constexpr int NG = 512;      // graphs
constexpr int H  = 16;       // hidden
constexpr int NB   = 128;    // coarse dst-buckets
constexpr int NPBK = 1172;   // nodes per bucket (128*1172 = 150016 >= NN)
constexpr int NBLK = 512;    // streaming blocks for hist/bucket
constexpr int CHUNK = (NE + NBLK - 1) / NBLK;   // 9375 edges per block
constexpr int NSLOT = 1536;  // csr scan slots (3 per thread x 512)

__device__ inline unsigned short f2bf(float f) {
    union { float f; unsigned u; } v; v.f = f;
    unsigned r = v.u + 0x7FFFu + ((v.u >> 16) & 1u);   // RNE
    return (unsigned short)(r >> 16);
}
__device__ inline float bf2f(unsigned short s) {
    union { unsigned u; float f; } v; v.u = ((unsigned)s) << 16;
    return v.f;
}

// ---------- phase A: per-block LDS histogram of dst buckets ----------
__global__ void k_hist(const int* __restrict__ dst, int* __restrict__ mat) {
    __shared__ int cnt[NB];
    for (int t = threadIdx.x; t < NB; t += 256) cnt[t] = 0;
    __syncthreads();
    int b = blockIdx.x;
    int e0 = b * CHUNK, e1 = min(e0 + CHUNK, NE);
    for (int e = e0 + (int)threadIdx.x; e < e1; e += 256)
        atomicAdd(&cnt[dst[e] / NPBK], 1);
    __syncthreads();
    for (int t = threadIdx.x; t < NB; t += 256) mat[b * NB + t] = cnt[t];
}

// ---------- column scan: mat[:,j] over NBLK blocks -> exclusive prefix, totals ----------
__global__ void k_scanb(int* __restrict__ mat, int* __restrict__ tot) {
    __shared__ int tmp[NBLK];
    int j = blockIdx.x, t = threadIdx.x;
    int v = mat[t * NB + j];
    tmp[t] = v;
    __syncthreads();
    for (int off = 1; off < NBLK; off <<= 1) {
        int a = (t >= off) ? tmp[t - off] : 0;
        __syncthreads();
        tmp[t] += a;
        __syncthreads();
    }
    mat[t * NB + j] = tmp[t] - v;               // exclusive within column
    if (t == NBLK - 1) tot[j] = tmp[t];
}

// ---------- bucket base scan (exclusive over NB buckets) ----------
__global__ void k_scant(const int* __restrict__ tot, int* __restrict__ base) {
    __shared__ int tmp[NB];
    int t = threadIdx.x;
    int v = tot[t];
    tmp[t] = v;
    __syncthreads();
    for (int off = 1; off < NB; off <<= 1) {
        int a = (t >= off) ? tmp[t - off] : 0;
        __syncthreads();
        tmp[t] += a;
        __syncthreads();
    }
    base[t] = tmp[t] - v;
    if (t == 0) base[NB] = NE;
}

// ---------- phase B: packed (src | local_dst<<18) grouped by bucket ----------
__global__ void k_bucket(const int* __restrict__ src, const int* __restrict__ dst,
                         const int* __restrict__ mat, const int* __restrict__ base,
                         unsigned* __restrict__ ed) {
    __shared__ int cur[NB];
    int b = blockIdx.x;
    if (threadIdx.x < NB) cur[threadIdx.x] = base[threadIdx.x] + mat[b * NB + threadIdx.x];
    __syncthreads();
    int e0 = b * CHUNK, e1 = min(e0 + CHUNK, NE);
    for (int e = e0 + (int)threadIdx.x; e < e1; e += 512) {
        int d = dst[e];
        int bq = d / NPBK;
        int p = atomicAdd(&cur[bq], 1);
        ed[p] = (unsigned)src[e] | ((unsigned)(d - bq * NPBK) << 18);
    }
}

// ---------- phase B2: per-bucket counting sort (NPBK=1172) -> CSR + disq ----------
__global__ void k_csr(const unsigned* __restrict__ ed, const int* __restrict__ base,
                      int* __restrict__ rs, int* __restrict__ csr,
                      float* __restrict__ disq) {
    __shared__ int cnt[NSLOT];
    __shared__ int exc[NSLOT];
    __shared__ int scn[512];
    int j = blockIdx.x, t = threadIdx.x;
    cnt[t] = 0; cnt[t + 512] = 0; cnt[t + 1024] = 0;
    __syncthreads();
    int e0 = base[j], e1 = base[j + 1];
    for (int e = e0 + t; e < e1; e += 512)
        atomicAdd(&cnt[ed[e] >> 18], 1);
    __syncthreads();
    // exclusive scan over 1536 slots: 3 elems/thread + Hillis-Steele + add-back
    int a0 = cnt[3 * t], a1 = cnt[3 * t + 1], a2 = cnt[3 * t + 2];
    int s = a0 + a1 + a2;
    scn[t] = s;
    __syncthreads();
    for (int off = 1; off < 512; off <<= 1) {
        int a = (t >= off) ? scn[t - off] : 0;
        __syncthreads();
        scn[t] += a;
        __syncthreads();
    }
    int eth = scn[t] - s;
    exc[3 * t] = eth;
    exc[3 * t + 1] = eth + a0;
    exc[3 * t + 2] = eth + a0 + a1;
    __syncthreads();
    int n0 = j * NPBK;
    for (int q = t; q < NPBK; q += 512) {
        int n = n0 + q;
        if (n < NN) {
            rs[n] = e0 + exc[q];
            disq[n] = rsqrtf((float)(cnt[q] + 1));   // +1 self-loop
        }
    }
    // cursors = exclusive offsets
    cnt[t] = exc[t]; cnt[t + 512] = exc[t + 512]; cnt[t + 1024] = exc[t + 1024];
    __syncthreads();
    for (int e = e0 + t; e < e1; e += 512) {
        unsigned ee = ed[e];
        int p = atomicAdd(&cnt[ee >> 18], 1);
        csr[e0 + p] = (int)(ee & 0x3FFFFu);
    }
    if (j == 0 && t == 0) rs[NN] = NE;
}

// ---------- y = (x @ W1) * disq  -> bf16 ----------
__global__ void k_xw1(const float* __restrict__ x, const float* __restrict__ W1,
                      const float* __restrict__ disq, unsigned short* __restrict__ y) {
    __shared__ float w[4 * H];
    if (threadIdx.x < 4 * H) w[threadIdx.x] = W1[threadIdx.x];
    __syncthreads();
    int i = blockIdx.x * blockDim.x + threadIdx.x;
    if (i >= NN) return;
    float4 xv = ((const float4*)x)[i];
    float d = disq[i];
    float o[H];
#pragma unroll
    for (int h = 0; h < H; ++h)
        o[h] = (xv.x * w[0*H + h] + xv.y * w[1*H + h] +
                xv.z * w[2*H + h] + xv.w * w[3*H + h]) * d;
    unsigned pk[8];
#pragma unroll
    for (int q = 0; q < 8; ++q)
        pk[q] = (unsigned)f2bf(o[2*q]) | ((unsigned)f2bf(o[2*q+1]) << 16);
    uint4* yp = (uint4*)(y + (size_t)i * H);
    yp[0] = make_uint4(pk[0], pk[1], pk[2], pk[3]);
    yp[1] = make_uint4(pk[4], pk[5], pk[6], pk[7]);
}

// ---------- gather: 16 lanes/node, 8-way unrolled for MLP ----------
__global__ void k_gather(const int* __restrict__ rs, const int* __restrict__ csr,
                         const unsigned short* __restrict__ y, const float* __restrict__ disq,
                         const float* __restrict__ b, float* __restrict__ hout) {
    int n    = blockIdx.x * 16 + (threadIdx.x >> 4);
    int lane = threadIdx.x & 15;
    if (n >= NN) return;
    int s0 = rs[n], s1 = rs[n + 1];
    float acc = bf2f(y[(size_t)n * H + lane]);   // self-loop term
    int k = s0;
    for (; k + 8 <= s1; k += 8) {
        int sa = csr[k+0], sb = csr[k+1], sc = csr[k+2], sd = csr[k+3];
        int se = csr[k+4], sf = csr[k+5], sg = csr[k+6], sh = csr[k+7];
        float v0 = bf2f(y[(size_t)sa * H + lane]);
        float v1 = bf2f(y[(size_t)sb * H + lane]);
        float v2 = bf2f(y[(size_t)sc * H + lane]);
        float v3 = bf2f(y[(size_t)sd * H + lane]);
        float v4 = bf2f(y[(size_t)se * H + lane]);
        float v5 = bf2f(y[(size_t)sf * H + lane]);
        float v6 = bf2f(y[(size_t)sg * H + lane]);
        float v7 = bf2f(y[(size_t)sh * H + lane]);
        acc += ((v0 + v1) + (v2 + v3)) + ((v4 + v5) + (v6 + v7));
    }
    for (; k < s1; ++k) acc += bf2f(y[(size_t)csr[k] * H + lane]);
    hout[(size_t)n * H + lane] = fmaxf(fmaf(acc, disq[n], b[lane]), 0.f);
}

// ---------- y = (h @ W2) * disq -> bf16 ----------
__global__ void k_hw2(const float* __restrict__ hin, const float* __restrict__ W2,
                      const float* __restrict__ disq, unsigned short* __restrict__ yout) {
    __shared__ float w[H * H];
    if (threadIdx.x < H * H) w[threadIdx.x] = W2[threadIdx.x];
    __syncthreads();
    int i = blockIdx.x * blockDim.x + threadIdx.x;
    if (i >= NN) return;
    float hv[H];
    const float4* hp = (const float4*)(hin + (size_t)i * H);
#pragma unroll
    for (int q = 0; q < 4; ++q) ((float4*)hv)[q] = hp[q];
    float d = disq[i];
    float o[H];
#pragma unroll
    for (int h = 0; h < H; ++h) {
        float s = 0.f;
#pragma unroll
        for (int k = 0; k < H; ++k) s += hv[k] * w[k*H + h];
        o[h] = s * d;
    }
    unsigned pk[8];
#pragma unroll
    for (int q = 0; q < 8; ++q)
        pk[q] = (unsigned)f2bf(o[2*q]) | ((unsigned)f2bf(o[2*q+1]) << 16);
    uint4* yp = (uint4*)(yout + (size_t)i * H);
    yp[0] = make_uint4(pk[0], pk[1], pk[2], pk[3]);
    yp[1] = make_uint4(pk[4], pk[5], pk[6], pk[7]);
}

// ---------- pool: one block per graph, 16 groups x 16 lanes + LDS tree ----------
__global__ void k_pool_blk(const float* __restrict__ h, const int* __restrict__ batch,
                           float* __restrict__ gout) {
    __shared__ float red[16][H + 1];
    int g    = blockIdx.x;
    int lane = threadIdx.x & 15;
    int grp  = threadIdx.x >> 4;                 // 0..15
    int lo = 0, hi = NN;
    while (lo < hi) { int m = (lo + hi) >> 1; if (batch[m] < g) lo = m + 1; else hi = m; }
    int start = lo;
    hi = NN;
    while (lo < hi) { int m = (lo + hi) >> 1; if (batch[m] < g + 1) lo = m + 1; else hi = m; }
    int end = lo;
    float acc = 0.f;
    for (int i = start + grp; i < end; i += 16)
        acc += h[(size_t)i * H + lane];
    red[grp][lane] = acc;
    __syncthreads();
    if (grp < 8) red[grp][lane] += red[grp + 8][lane];
    __syncthreads();
    if (grp < 4) red[grp][lane] += red[grp + 4][lane];
    __syncthreads();
    if (grp < 2) red[grp][lane] += red[grp + 2][lane];
    __syncthreads();
    if (grp == 0)
        gout[(size_t)g * H + lane] = red[0][lane] + red[1][lane];
}

// ---------- final MLP ----------
__global__ void k_mlp(const float* __restrict__ g, const float* __restrict__ Wf1,
                      const float* __restrict__ bf1, const float* __restrict__ Wf2,
                      const float* __restrict__ bf2, float* __restrict__ out) {
    __shared__ float w1[H * H];
    __shared__ float b1s[H];
    __shared__ float w2[H];
    __shared__ float b2s;
    if (threadIdx.x < H * H) w1[threadIdx.x] = Wf1[threadIdx.x];
    if (threadIdx.x < H) { b1s[threadIdx.x] = bf1[threadIdx.x]; w2[threadIdx.x] = Wf2[threadIdx.x]; }
    if (threadIdx.x == 0) b2s = bf2[0];
    __syncthreads();
    int i = blockIdx.x * blockDim.x + threadIdx.x;
    if (i >= NG) return;
    float gv[H];
    const float4* gp = (const float4*)(g + (size_t)i * H);
#pragma unroll
    for (int q = 0; q < 4; ++q) ((float4*)gv)[q] = gp[q];
    float s2 = 0.f;
#pragma unroll
    for (int h = 0; h < H; ++h) {
        float t = b1s[h];
#pragma unroll
        for (int k = 0; k < H; ++k) t += gv[k] * w1[k*H + h];
        s2 += fmaxf(t, 0.f) * w2[h];
    }
    out[i] = s2 + b2s;
}

// ================= fallback (baseline atomic path, f32) =================
__global__ void k_deg_init(float* __restrict__ deg) {
    int i = blockIdx.x * blockDim.x + threadIdx.x;
    if (i < NN) deg[i] = 1.0f;
}
__global__ void k_deg_edges(const int* __restrict__ dst, float* __restrict__ deg) {
    int i = blockIdx.x * blockDim.x + threadIdx.x;
    if (i < NE) atomicAdd(&deg[dst[i]], 1.0f);
}
__global__ void k_disq(float* __restrict__ deg) {
    int i = blockIdx.x * blockDim.x + threadIdx.x;
    if (i < NN) deg[i] = rsqrtf(deg[i]);
}
__global__ void k_xw1f(const float* __restrict__ x, const float* __restrict__ W1,
                       const float* __restrict__ disq, float* __restrict__ y) {
    __shared__ float w[4 * H];
    if (threadIdx.x < 4 * H) w[threadIdx.x] = W1[threadIdx.x];
    __syncthreads();
    int i = blockIdx.x * blockDim.x + threadIdx.x;
    if (i >= NN) return;
    float4 xv = ((const float4*)x)[i];
    float d = disq[i];
    float o[H];
#pragma unroll
    for (int h = 0; h < H; ++h)
        o[h] = (xv.x * w[0*H + h] + xv.y * w[1*H + h] +
                xv.z * w[2*H + h] + xv.w * w[3*H + h]) * d;
    float4* yp = (float4*)(y + (size_t)i * H);
#pragma unroll
    for (int q = 0; q < 4; ++q) yp[q] = ((float4*)o)[q];
}
__global__ void k_hw2f(const float* __restrict__ hin, const float* __restrict__ W2,
                       const float* __restrict__ disq, float* __restrict__ yout) {
    __shared__ float w[H * H];
    if (threadIdx.x < H * H) w[threadIdx.x] = W2[threadIdx.x];
    __syncthreads();
    int i = blockIdx.x * blockDim.x + threadIdx.x;
    if (i >= NN) return;
    float hv[H];
    const float4* hp = (const float4*)(hin + (size_t)i * H);
#pragma unroll
    for (int q = 0; q < 4; ++q) ((float4*)hv)[q] = hp[q];
    float d = disq[i];
    float o[H];
#pragma unroll
    for (int h = 0; h < H; ++h) {
        float s = 0.f;
#pragma unroll
        for (int k = 0; k < H; ++k) s += hv[k] * w[k*H + h];
        o[h] = s * d;
    }
    float4* yp = (float4*)(yout + (size_t)i * H);
#pragma unroll
    for (int q = 0; q < 4; ++q) yp[q] = ((float4*)o)[q];
}
__global__ void k_scatter(const int* __restrict__ src, const int* __restrict__ dst,
                          const float* __restrict__ y, float* __restrict__ acc) {
    int i = blockIdx.x * blockDim.x + threadIdx.x;
    if (i >= NE) return;
    int s = src[i], d = dst[i];
    const float4* yp = (const float4*)(y + (size_t)s * H);
    float* ap = acc + (size_t)d * H;
#pragma unroll
    for (int q = 0; q < 4; ++q) {
        float4 v = yp[q];
        atomicAdd(ap + q*4 + 0, v.x);
        atomicAdd(ap + q*4 + 1, v.y);
        atomicAdd(ap + q*4 + 2, v.z);
        atomicAdd(ap + q*4 + 3, v.w);
    }
}
__global__ void k_post(const float* __restrict__ acc, const float* __restrict__ disq,
                       const float* __restrict__ b, float* __restrict__ hout) {
    __shared__ float bs[H];
    if (threadIdx.x < H) bs[threadIdx.x] = b[threadIdx.x];
    __syncthreads();
    int i = blockIdx.x * blockDim.x + threadIdx.x;
    if (i >= NN) return;
    float d = disq[i];
    const float4* ap = (const float4*)(acc + (size_t)i * H);
    float4* hp = (float4*)(hout + (size_t)i * H);
#pragma unroll
    for (int q = 0; q < 4; ++q) {
        float4 v = ap[q];
        float4 r;
        r.x = fmaxf(v.x * d + bs[q*4+0], 0.f);
        r.y = fmaxf(v.y * d + bs[q*4+1], 0.f);
        r.z = fmaxf(v.z * d + bs[q*4+2], 0.f);
        r.w = fmaxf(v.w * d + bs[q*4+3], 0.f);
        hp[q] = r;
    }
}

extern "C" void kernel_launch(void* const* d_in, const int* in_sizes, int n_in,
                              void* d_out, int out_size, void* d_ws, size_t ws_size,
                              hipStream_t stream) {
    const float* x   = (const float*)d_in[0];
    const float* W1  = (const float*)d_in[1];
    const float* b1  = (const float*)d_in[2];
    const float* W2  = (const float*)d_in[3];
    const float* b2  = (const float*)d_in[4];
    const float* Wf1 = (const float*)d_in[5];
    const float* bf1 = (const float*)d_in[6];
    const float* Wf2 = (const float*)d_in[7];
    const float* bf2 = (const float*)d_in[8];
    const int*   ei    = (const int*)d_in[9];
    const int*   batch = (const int*)d_in[10];
    const int* src = ei;        // edge_index row 0
    const int* dst = ei + NE;   // edge_index row 1
    float* out = (float*)d_out;

    const int BT  = 256;
    const int gbN = (NN + BT - 1) / BT;               // 586
    const int gbE = (NE + BT - 1) / BT;               // 18750 (fallback)
    const int NPB = BT / H;                           // 16
    const int gbG = (NN + NPB - 1) / NPB;             // 9375 gather blocks

    // ---- workspace layout (4-byte words; region starts 16B-aligned) ----
    // mat[512*128] | tot[128] | base[129]pad | ed[NE] | csr[NE] | rs[NN+1]pad |
    // disq[NN] | ybf[NN*H bf16] | bufB[NN*H f32] | g[NG*H]
    size_t need = ((size_t)13573992) * 4;   // ~54.3 MB
    if (ws_size >= need) {
        int*      mat  = (int*)d_ws;                   // 65536
        int*      tot  = mat + 65536;                  // 128
        int*      base = mat + 65664;                  // 129 (pad to 65796)
        unsigned* ed   = (unsigned*)(mat + 65796);     // NE
        int*      csr  = mat + 4865796;                // NE
        int*      rs   = mat + 9665796;                // NN+1 (pad to 9815800)
        float*    disq = (float*)(mat + 9815800);      // NN
        unsigned short* ybf = (unsigned short*)(mat + 9965800); // NN*H bf16
        float*    bufB = (float*)(mat + 11165800);     // NN*H
        float*    g    = (float*)(mat + 13565800);     // NG*H

        // graph bucketing + per-bucket counting sort -> CSR (no global atomics)
        k_hist  <<<NBLK, 256, 0, stream>>>(dst, mat);
        k_scanb <<<NB,   NBLK, 0, stream>>>(mat, tot);
        k_scant <<<1,    NB,  0, stream>>>(tot, base);
        k_bucket<<<NBLK, 512, 0, stream>>>(src, dst, mat, base, ed);
        k_csr   <<<NB,   512, 0, stream>>>(ed, base, rs, csr, disq);

        // conv1
        k_xw1   <<<gbN, 256, 0, stream>>>(x, W1, disq, ybf);
        k_gather<<<gbG, 256, 0, stream>>>(rs, csr, ybf, disq, b1, bufB);   // h1
        // conv2
        k_hw2   <<<gbN, 256, 0, stream>>>(bufB, W2, disq, ybf);            // y2
        k_gather<<<gbG, 256, 0, stream>>>(rs, csr, ybf, disq, b2, bufB);   // h2
        // pool + MLP
        k_pool_blk<<<NG, 256, 0, stream>>>(bufB, batch, g);
        k_mlp<<<1, 512, 0, stream>>>(g, Wf1, bf1, Wf2, bf2, out);
    } else {
        // fallback: baseline atomic-scatter path (~20 MB ws, f32)
        float* disq = (float*)d_ws;
        float* bufA = disq + NN;
        float* bufB = bufA + (size_t)NN * H;
        float* g    = bufB + (size_t)NN * H;

        k_deg_init<<<gbN, BT, 0, stream>>>(disq);
        k_deg_edges<<<gbE, BT, 0, stream>>>(dst, disq);
        k_disq<<<gbN, BT, 0, stream>>>(disq);

        k_xw1f<<<gbN, BT, 0, stream>>>(x, W1, disq, bufA);
        hipMemcpyAsync(bufB, bufA, (size_t)NN * H * sizeof(float),
                       hipMemcpyDeviceToDevice, stream);
        k_scatter<<<gbE, BT, 0, stream>>>(src, dst, bufA, bufB);
        k_post<<<gbN, BT, 0, stream>>>(bufB, disq, b1, bufA);

        k_hw2f<<<gbN, BT, 0, stream>>>(bufA, W2, disq, bufB);
        hipMemcpyAsync(bufA, bufB, (size_t)NN * H * sizeof(float),
                       hipMemcpyDeviceToDevice, stream);
        k_scatter<<<gbE, BT, 0, stream>>>(src, dst, bufB, bufA);
        k_post<<<gbN, BT, 0, stream>>>(bufA, disq, b2, bufB);

        k_pool_blk<<<NG, BT, 0, stream>>>(bufB, batch, g);
        k_mlp<<<1, 512, 0, stream>>>(g, Wf1, bf1, Wf2, bf2, out);
    }
}

// Round 14
// 232.785 us; speedup vs baseline: 4.3472x; 1.0367x over previous
//
#include <hip/hip_runtime.h>

constexpr int NN = 150000;   // nodes
constexpr int NE = 4800000;  // edges
constexpr int NG = 512;      // graphs
constexpr int H  = 16;       // hidden
constexpr int NB   = 512;    // coarse dst-buckets
constexpr int NPBK = 293;    // nodes per bucket (512*293 = 150016 >= NN)
constexpr int NBLK = 128;    // streaming blocks for hist/bucket (runs = 73 edges)
constexpr int CHUNK = (NE + NBLK - 1) / NBLK;   // 37500 edges per block
constexpr int CAP = 11776;   // LDS staging capacity per bucket (mean 9375, +24 sigma)

__device__ inline unsigned short f2bf(float f) {
    union { float f; unsigned u; } v; v.f = f;
    unsigned r = v.u + 0x7FFFu + ((v.u >> 16) & 1u);   // RNE
    return (unsigned short)(r >> 16);
}
__device__ inline float bf2f(unsigned short s) {
    union { unsigned u; float f; } v; v.u = ((unsigned)s) << 16;
    return v.f;
}

// ---------- phase A: per-block LDS histogram of dst buckets ----------
__global__ void k_hist(const int* __restrict__ dst, int* __restrict__ mat) {
    __shared__ int cnt[NB];
    if (threadIdx.x < NB) cnt[threadIdx.x] = 0;
    __syncthreads();
    int b = blockIdx.x;
    int e0 = b * CHUNK, e1 = min(e0 + CHUNK, NE);
    for (int e = e0 + (int)threadIdx.x; e < e1; e += 512)
        atomicAdd(&cnt[dst[e] / NPBK], 1);
    __syncthreads();
    if (threadIdx.x < NB) mat[b * NB + threadIdx.x] = cnt[threadIdx.x];
}

// ---------- column scan: mat[:,j] over NBLK blocks -> exclusive prefix, totals ----------
__global__ void k_scanb(int* __restrict__ mat, int* __restrict__ tot) {
    __shared__ int tmp[NBLK];
    int j = blockIdx.x, t = threadIdx.x;
    int v = mat[t * NB + j];
    tmp[t] = v;
    __syncthreads();
    for (int off = 1; off < NBLK; off <<= 1) {
        int a = (t >= off) ? tmp[t - off] : 0;
        __syncthreads();
        tmp[t] += a;
        __syncthreads();
    }
    mat[t * NB + j] = tmp[t] - v;               // exclusive within column
    if (t == NBLK - 1) tot[j] = tmp[t];
}

// ---------- bucket base scan (exclusive over NB buckets) ----------
__global__ void k_scant(const int* __restrict__ tot, int* __restrict__ base) {
    __shared__ int tmp[NB];
    int t = threadIdx.x;
    int v = tot[t];
    tmp[t] = v;
    __syncthreads();
    for (int off = 1; off < NB; off <<= 1) {
        int a = (t >= off) ? tmp[t - off] : 0;
        __syncthreads();
        tmp[t] += a;
        __syncthreads();
    }
    base[t] = tmp[t] - v;
    if (t == 0) base[NB] = NE;
}

// ---------- phase B: packed (src | local_dst<<18) grouped by bucket ----------
__global__ void k_bucket(const int* __restrict__ src, const int* __restrict__ dst,
                         const int* __restrict__ mat, const int* __restrict__ base,
                         unsigned* __restrict__ ed) {
    __shared__ int cur[NB];
    int b = blockIdx.x;
    if (threadIdx.x < NB) cur[threadIdx.x] = base[threadIdx.x] + mat[b * NB + threadIdx.x];
    __syncthreads();
    int e0 = b * CHUNK, e1 = min(e0 + CHUNK, NE);
    for (int e = e0 + (int)threadIdx.x; e < e1; e += 512) {
        int d = dst[e];
        int bq = d / NPBK;
        int p = atomicAdd(&cur[bq], 1);
        ed[p] = (unsigned)src[e] | ((unsigned)(d - bq * NPBK) << 18);
    }
}

// ---------- phase B2: per-bucket counting sort, LDS-staged coalesced csr write ----------
__global__ void k_csr2(const unsigned* __restrict__ ed, const int* __restrict__ base,
                       int* __restrict__ rs, int* __restrict__ csr,
                       float* __restrict__ disq) {
    __shared__ int cnt[NB];          // 1 counter per thread slot (NPBK=293 used)
    __shared__ int scn[NB];
    __shared__ int stg[CAP];         // 46 KB staging
    int j = blockIdx.x, t = threadIdx.x;
    cnt[t] = 0;
    __syncthreads();
    int e0 = base[j], e1 = base[j + 1];
    int m = e1 - e0;
    for (int e = e0 + t; e < e1; e += 512)
        atomicAdd(&cnt[ed[e] >> 18], 1);
    __syncthreads();
    int v = cnt[t];
    scn[t] = v;
    __syncthreads();
    for (int off = 1; off < NB; off <<= 1) {
        int a = (t >= off) ? scn[t - off] : 0;
        __syncthreads();
        scn[t] += a;
        __syncthreads();
    }
    int excl = scn[t] - v;
    int n0 = j * NPBK;
    int n = n0 + t;
    if (t < NPBK && n < NN) {
        rs[n] = e0 + excl;
        disq[n] = rsqrtf((float)(v + 1));        // +1 self-loop
    }
    cnt[t] = excl;                               // cursors
    __syncthreads();
    if (m <= CAP) {
        for (int e = e0 + t; e < e1; e += 512) {
            unsigned ee = ed[e];
            int p = atomicAdd(&cnt[ee >> 18], 1);
            stg[p] = (int)(ee & 0x3FFFFu);
        }
        __syncthreads();
        for (int k = t; k < m; k += 512) csr[e0 + k] = stg[k];   // coalesced
    } else {
        for (int e = e0 + t; e < e1; e += 512) {
            unsigned ee = ed[e];
            int p = atomicAdd(&cnt[ee >> 18], 1);
            csr[e0 + p] = (int)(ee & 0x3FFFFu);
        }
    }
    if (j == 0 && t == 0) rs[NN] = NE;
}

// ---------- y = (x @ W1) * disq  -> bf16 ----------
__global__ void k_xw1(const float* __restrict__ x, const float* __restrict__ W1,
                      const float* __restrict__ disq, unsigned short* __restrict__ y) {
    __shared__ float w[4 * H];
    if (threadIdx.x < 4 * H) w[threadIdx.x] = W1[threadIdx.x];
    __syncthreads();
    int i = blockIdx.x * blockDim.x + threadIdx.x;
    if (i >= NN) return;
    float4 xv = ((const float4*)x)[i];
    float d = disq[i];
    float o[H];
#pragma unroll
    for (int h = 0; h < H; ++h)
        o[h] = (xv.x * w[0*H + h] + xv.y * w[1*H + h] +
                xv.z * w[2*H + h] + xv.w * w[3*H + h]) * d;
    unsigned pk[8];
#pragma unroll
    for (int q = 0; q < 8; ++q)
        pk[q] = (unsigned)f2bf(o[2*q]) | ((unsigned)f2bf(o[2*q+1]) << 16);
    uint4* yp = (uint4*)(y + (size_t)i * H);
    yp[0] = make_uint4(pk[0], pk[1], pk[2], pk[3]);
    yp[1] = make_uint4(pk[4], pk[5], pk[6], pk[7]);
}

// ---------- gather: 16 lanes/node, 8-way unrolled for MLP ----------
__global__ void k_gather(const int* __restrict__ rs, const int* __restrict__ csr,
                         const unsigned short* __restrict__ y, const float* __restrict__ disq,
                         const float* __restrict__ b, float* __restrict__ hout) {
    int n    = blockIdx.x * 16 + (threadIdx.x >> 4);
    int lane = threadIdx.x & 15;
    if (n >= NN) return;
    int s0 = rs[n], s1 = rs[n + 1];
    float acc = bf2f(y[(size_t)n * H + lane]);   // self-loop term
    int k = s0;
    for (; k + 8 <= s1; k += 8) {
        int sa = csr[k+0], sb = csr[k+1], sc = csr[k+2], sd = csr[k+3];
        int se = csr[k+4], sf = csr[k+5], sg = csr[k+6], sh = csr[k+7];
        float v0 = bf2f(y[(size_t)sa * H + lane]);
        float v1 = bf2f(y[(size_t)sb * H + lane]);
        float v2 = bf2f(y[(size_t)sc * H + lane]);
        float v3 = bf2f(y[(size_t)sd * H + lane]);
        float v4 = bf2f(y[(size_t)se * H + lane]);
        float v5 = bf2f(y[(size_t)sf * H + lane]);
        float v6 = bf2f(y[(size_t)sg * H + lane]);
        float v7 = bf2f(y[(size_t)sh * H + lane]);
        acc += ((v0 + v1) + (v2 + v3)) + ((v4 + v5) + (v6 + v7));
    }
    for (; k < s1; ++k) acc += bf2f(y[(size_t)csr[k] * H + lane]);
    hout[(size_t)n * H + lane] = fmaxf(fmaf(acc, disq[n], b[lane]), 0.f);
}

// ---------- y = (h @ W2) * disq -> bf16 ----------
__global__ void k_hw2(const float* __restrict__ hin, const float* __restrict__ W2,
                      const float* __restrict__ disq, unsigned short* __restrict__ yout) {
    __shared__ float w[H * H];
    if (threadIdx.x < H * H) w[threadIdx.x] = W2[threadIdx.x];
    __syncthreads();
    int i = blockIdx.x * blockDim.x + threadIdx.x;
    if (i >= NN) return;
    float hv[H];
    const float4* hp = (const float4*)(hin + (size_t)i * H);
#pragma unroll
    for (int q = 0; q < 4; ++q) ((float4*)hv)[q] = hp[q];
    float d = disq[i];
    float o[H];
#pragma unroll
    for (int h = 0; h < H; ++h) {
        float s = 0.f;
#pragma unroll
        for (int k = 0; k < H; ++k) s += hv[k] * w[k*H + h];
        o[h] = s * d;
    }
    unsigned pk[8];
#pragma unroll
    for (int q = 0; q < 8; ++q)
        pk[q] = (unsigned)f2bf(o[2*q]) | ((unsigned)f2bf(o[2*q+1]) << 16);
    uint4* yp = (uint4*)(yout + (size_t)i * H);
    yp[0] = make_uint4(pk[0], pk[1], pk[2], pk[3]);
    yp[1] = make_uint4(pk[4], pk[5], pk[6], pk[7]);
}

// ---------- pool: one block per graph, 16 groups x 16 lanes + LDS tree ----------
__global__ void k_pool_blk(const float* __restrict__ h, const int* __restrict__ batch,
                           float* __restrict__ gout) {
    __shared__ float red[16][H + 1];
    int g    = blockIdx.x;
    int lane = threadIdx.x & 15;
    int grp  = threadIdx.x >> 4;                 // 0..15
    int lo = 0, hi = NN;
    while (lo < hi) { int m = (lo + hi) >> 1; if (batch[m] < g) lo = m + 1; else hi = m; }
    int start = lo;
    hi = NN;
    while (lo < hi) { int m = (lo + hi) >> 1; if (batch[m] < g + 1) lo = m + 1; else hi = m; }
    int end = lo;
    float acc = 0.f;
    for (int i = start + grp; i < end; i += 16)
        acc += h[(size_t)i * H + lane];
    red[grp][lane] = acc;
    __syncthreads();
    if (grp < 8) red[grp][lane] += red[grp + 8][lane];
    __syncthreads();
    if (grp < 4) red[grp][lane] += red[grp + 4][lane];
    __syncthreads();
    if (grp < 2) red[grp][lane] += red[grp + 2][lane];
    __syncthreads();
    if (grp == 0)
        gout[(size_t)g * H + lane] = red[0][lane] + red[1][lane];
}

// ---------- final MLP ----------
__global__ void k_mlp(const float* __restrict__ g, const float* __restrict__ Wf1,
                      const float* __restrict__ bf1, const float* __restrict__ Wf2,
                      const float* __restrict__ bf2, float* __restrict__ out) {
    __shared__ float w1[H * H];
    __shared__ float b1s[H];
    __shared__ float w2[H];
    __shared__ float b2s;
    if (threadIdx.x < H * H) w1[threadIdx.x] = Wf1[threadIdx.x];
    if (threadIdx.x < H) { b1s[threadIdx.x] = bf1[threadIdx.x]; w2[threadIdx.x] = Wf2[threadIdx.x]; }
    if (threadIdx.x == 0) b2s = bf2[0];
    __syncthreads();
    int i = blockIdx.x * blockDim.x + threadIdx.x;
    if (i >= NG) return;
    float gv[H];
    const float4* gp = (const float4*)(g + (size_t)i * H);
#pragma unroll
    for (int q = 0; q < 4; ++q) ((float4*)gv)[q] = gp[q];
    float s2 = 0.f;
#pragma unroll
    for (int h = 0; h < H; ++h) {
        float t = b1s[h];
#pragma unroll
        for (int k = 0; k < H; ++k) t += gv[k] * w1[k*H + h];
        s2 += fmaxf(t, 0.f) * w2[h];
    }
    out[i] = s2 + b2s;
}

// ================= fallback (baseline atomic path, f32) =================
__global__ void k_deg_init(float* __restrict__ deg) {
    int i = blockIdx.x * blockDim.x + threadIdx.x;
    if (i < NN) deg[i] = 1.0f;
}
__global__ void k_deg_edges(const int* __restrict__ dst, float* __restrict__ deg) {
    int i = blockIdx.x * blockDim.x + threadIdx.x;
    if (i < NE) atomicAdd(&deg[dst[i]], 1.0f);
}
__global__ void k_disq(float* __restrict__ deg) {
    int i = blockIdx.x * blockDim.x + threadIdx.x;
    if (i < NN) deg[i] = rsqrtf(deg[i]);
}
__global__ void k_xw1f(const float* __restrict__ x, const float* __restrict__ W1,
                       const float* __restrict__ disq, float* __restrict__ y) {
    __shared__ float w[4 * H];
    if (threadIdx.x < 4 * H) w[threadIdx.x] = W1[threadIdx.x];
    __syncthreads();
    int i = blockIdx.x * blockDim.x + threadIdx.x;
    if (i >= NN) return;
    float4 xv = ((const float4*)x)[i];
    float d = disq[i];
    float o[H];
#pragma unroll
    for (int h = 0; h < H; ++h)
        o[h] = (xv.x * w[0*H + h] + xv.y * w[1*H + h] +
                xv.z * w[2*H + h] + xv.w * w[3*H + h]) * d;
    float4* yp = (float4*)(y + (size_t)i * H);
#pragma unroll
    for (int q = 0; q < 4; ++q) yp[q] = ((float4*)o)[q];
}
__global__ void k_hw2f(const float* __restrict__ hin, const float* __restrict__ W2,
                       const float* __restrict__ disq, float* __restrict__ yout) {
    __shared__ float w[H * H];
    if (threadIdx.x < H * H) w[threadIdx.x] = W2[threadIdx.x];
    __syncthreads();
    int i = blockIdx.x * blockDim.x + threadIdx.x;
    if (i >= NN) return;
    float hv[H];
    const float4* hp = (const float4*)(hin + (size_t)i * H);
#pragma unroll
    for (int q = 0; q < 4; ++q) ((float4*)hv)[q] = hp[q];
    float d = disq[i];
    float o[H];
#pragma unroll
    for (int h = 0; h < H; ++h) {
        float s = 0.f;
#pragma unroll
        for (int k = 0; k < H; ++k) s += hv[k] * w[k*H + h];
        o[h] = s * d;
    }
    float4* yp = (float4*)(yout + (size_t)i * H);
#pragma unroll
    for (int q = 0; q < 4; ++q) yp[q] = ((float4*)o)[q];
}
__global__ void k_scatter(const int* __restrict__ src, const int* __restrict__ dst,
                          const float* __restrict__ y, float* __restrict__ acc) {
    int i = blockIdx.x * blockDim.x + threadIdx.x;
    if (i >= NE) return;
    int s = src[i], d = dst[i];
    const float4* yp = (const float4*)(y + (size_t)s * H);
    float* ap = acc + (size_t)d * H;
#pragma unroll
    for (int q = 0; q < 4; ++q) {
        float4 v = yp[q];
        atomicAdd(ap + q*4 + 0, v.x);
        atomicAdd(ap + q*4 + 1, v.y);
        atomicAdd(ap + q*4 + 2, v.z);
        atomicAdd(ap + q*4 + 3, v.w);
    }
}
__global__ void k_post(const float* __restrict__ acc, const float* __restrict__ disq,
                       const float* __restrict__ b, float* __restrict__ hout) {
    __shared__ float bs[H];
    if (threadIdx.x < H) bs[threadIdx.x] = b[threadIdx.x];
    __syncthreads();
    int i = blockIdx.x * blockDim.x + threadIdx.x;
    if (i >= NN) return;
    float d = disq[i];
    const float4* ap = (const float4*)(acc + (size_t)i * H);
    float4* hp = (float4*)(hout + (size_t)i * H);
#pragma unroll
    for (int q = 0; q < 4; ++q) {
        float4 v = ap[q];
        float4 r;
        r.x = fmaxf(v.x * d + bs[q*4+0], 0.f);
        r.y = fmaxf(v.y * d + bs[q*4+1], 0.f);
        r.z = fmaxf(v.z * d + bs[q*4+2], 0.f);
        r.w = fmaxf(v.w * d + bs[q*4+3], 0.f);
        hp[q] = r;
    }
}

extern "C" void kernel_launch(void* const* d_in, const int* in_sizes, int n_in,
                              void* d_out, int out_size, void* d_ws, size_t ws_size,
                              hipStream_t stream) {
    const float* x   = (const float*)d_in[0];
    const float* W1  = (const float*)d_in[1];
    const float* b1  = (const float*)d_in[2];
    const float* W2  = (const float*)d_in[3];
    const float* b2  = (const float*)d_in[4];
    const float* Wf1 = (const float*)d_in[5];
    const float* bf1 = (const float*)d_in[6];
    const float* Wf2 = (const float*)d_in[7];
    const float* bf2 = (const float*)d_in[8];
    const int*   ei    = (const int*)d_in[9];
    const int*   batch = (const int*)d_in[10];
    const int* src = ei;        // edge_index row 0
    const int* dst = ei + NE;   // edge_index row 1
    float* out = (float*)d_out;

    const int BT  = 256;
    const int gbN = (NN + BT - 1) / BT;               // 586
    const int gbE = (NE + BT - 1) / BT;               // 18750 (fallback)
    const int NPB = BT / H;                           // 16
    const int gbG = (NN + NPB - 1) / NPB;             // 9375 gather blocks

    // ---- workspace layout (4-byte words; region starts 16B-aligned) ----
    // mat[128*512] | tot[512] | base[513]pad | ed[NE] | csr[NE] | rs[NN+1]pad |
    // disq[NN] | ybf[NN*H bf16] | bufB[NN*H f32] | g[NG*H]
    size_t need = ((size_t)13574760) * 4;   // ~54.3 MB
    if (ws_size >= need) {
        int*      mat  = (int*)d_ws;                   // 65536
        int*      tot  = mat + 65536;                  // 512
        int*      base = mat + 66048;                  // 513 (pad to 66564)
        unsigned* ed   = (unsigned*)(mat + 66564);     // NE
        int*      csr  = mat + 4866564;                // NE
        int*      rs   = mat + 9666564;                // NN+1 (pad to 9816568)
        float*    disq = (float*)(mat + 9816568);      // NN
        unsigned short* ybf = (unsigned short*)(mat + 9966568); // NN*H bf16
        float*    bufB = (float*)(mat + 11166568);     // NN*H
        float*    g    = (float*)(mat + 13566568);     // NG*H

        // graph bucketing + LDS-staged per-bucket counting sort -> CSR
        k_hist  <<<NBLK, 512, 0, stream>>>(dst, mat);
        k_scanb <<<NB,   NBLK, 0, stream>>>(mat, tot);
        k_scant <<<1,    NB,  0, stream>>>(tot, base);
        k_bucket<<<NBLK, 512, 0, stream>>>(src, dst, mat, base, ed);
        k_csr2  <<<NB,   512, 0, stream>>>(ed, base, rs, csr, disq);

        // conv1
        k_xw1   <<<gbN, 256, 0, stream>>>(x, W1, disq, ybf);
        k_gather<<<gbG, 256, 0, stream>>>(rs, csr, ybf, disq, b1, bufB);   // h1
        // conv2
        k_hw2   <<<gbN, 256, 0, stream>>>(bufB, W2, disq, ybf);            // y2
        k_gather<<<gbG, 256, 0, stream>>>(rs, csr, ybf, disq, b2, bufB);   // h2
        // pool + MLP
        k_pool_blk<<<NG, 256, 0, stream>>>(bufB, batch, g);
        k_mlp<<<1, 512, 0, stream>>>(g, Wf1, bf1, Wf2, bf2, out);
    } else {
        // fallback: baseline atomic-scatter path (~20 MB ws, f32)
        float* disq = (float*)d_ws;
        float* bufA = disq + NN;
        float* bufB = bufA + (size_t)NN * H;
        float* g    = bufB + (size_t)NN * H;

        k_deg_init<<<gbN, BT, 0, stream>>>(disq);
        k_deg_edges<<<gbE, BT, 0, stream>>>(dst, disq);
        k_disq<<<gbN, BT, 0, stream>>>(disq);

        k_xw1f<<<gbN, BT, 0, stream>>>(x, W1, disq, bufA);
        hipMemcpyAsync(bufB, bufA, (size_t)NN * H * sizeof(float),
                       hipMemcpyDeviceToDevice, stream);
        k_scatter<<<gbE, BT, 0, stream>>>(src, dst, bufA, bufB);
        k_post<<<gbN, BT, 0, stream>>>(bufB, disq, b1, bufA);

        k_hw2f<<<gbN, BT, 0, stream>>>(bufA, W2, disq, bufB);
        hipMemcpyAsync(bufA, bufB, (size_t)NN * H * sizeof(float),
                       hipMemcpyDeviceToDevice, stream);
        k_scatter<<<gbE, BT, 0, stream>>>(src, dst, bufB, bufA);
        k_post<<<gbN, BT, 0, stream>>>(bufA, disq, b2, bufB);

        k_pool_blk<<<NG, BT, 0, stream>>>(bufB, batch, g);
        k_mlp<<<1, 512, 0, stream>>>(g, Wf1, bf1, Wf2, bf2, out);
    }
}

// Round 15
// 224.337 us; speedup vs baseline: 4.5109x; 1.0377x over previous
//
#include <hip/hip_runtime.h>

constexpr int NN = 150000;   // nodes
constexpr int NE = 4800000;  // edges
constexpr int NG = 512;      // graphs
constexpr int H  = 16;       // hidden
constexpr int NB   = 512;    // coarse dst-buckets
constexpr int NPBK = 293;    // nodes per bucket (512*293 = 150016 >= NN)
constexpr int NBLK = 256;    // streaming blocks for hist/part
constexpr int CHUNK = NE / NBLK;   // 18750 edges per block (exact)
constexpr int CAP = 11776;   // k_csr2 LDS staging capacity (mean 9375, +24 sigma)

__device__ inline unsigned short f2bf(float f) {
    union { float f; unsigned u; } v; v.f = f;
    unsigned r = v.u + 0x7FFFu + ((v.u >> 16) & 1u);   // RNE
    return (unsigned short)(r >> 16);
}
__device__ inline float bf2f(unsigned short s) {
    union { unsigned u; float f; } v; v.u = ((unsigned)s) << 16;
    return v.f;
}

// ---------- phase A: per-block LDS histogram -> global bucket totals ----------
__global__ void k_hist2(const int* __restrict__ dst, int* __restrict__ tot) {
    __shared__ int cnt[NB];
    cnt[threadIdx.x] = 0;
    __syncthreads();
    int b = blockIdx.x;
    int e0 = b * CHUNK, e1 = min(e0 + CHUNK, NE);
    for (int e = e0 + (int)threadIdx.x; e < e1; e += 512)
        atomicAdd(&cnt[dst[e] / NPBK], 1);
    __syncthreads();
    if (cnt[threadIdx.x] > 0) atomicAdd(&tot[threadIdx.x], cnt[threadIdx.x]);
}

// ---------- bucket base scan (exclusive) + cursor init ----------
__global__ void k_scant2(const int* __restrict__ tot, int* __restrict__ base,
                         int* __restrict__ cur) {
    __shared__ int tmp[NB];
    int t = threadIdx.x;
    int v = tot[t];
    tmp[t] = v;
    __syncthreads();
    for (int off = 1; off < NB; off <<= 1) {
        int a = (t >= off) ? tmp[t - off] : 0;
        __syncthreads();
        tmp[t] += a;
        __syncthreads();
    }
    base[t] = tmp[t] - v;
    cur[t]  = tmp[t] - v;
    if (t == 0) base[NB] = NE;
}

// ---------- phase B: LDS-staged partition, coalesced run writeout ----------
__global__ void k_part(const int* __restrict__ src, const int* __restrict__ dst,
                       int* __restrict__ cur, unsigned* __restrict__ ed) {
    __shared__ int cnt[NB];
    __shared__ int off[NB];          // exclusive local offsets
    __shared__ int gsnap[NB];        // global run base (cursor snapshot)
    __shared__ int lcur[NB];         // local scatter cursors
    __shared__ unsigned stg[CHUNK];  // 75 KB staging
    int b = blockIdx.x, t = threadIdx.x;
    cnt[t] = 0;
    __syncthreads();
    int e0 = b * CHUNK, e1 = min(e0 + CHUNK, NE);
    // pass 1: count
    for (int e = e0 + t; e < e1; e += 512)
        atomicAdd(&cnt[dst[e] / NPBK], 1);
    __syncthreads();
    // scan -> exclusive local offsets
    int v = cnt[t];
    off[t] = v;
    __syncthreads();
    for (int o = 1; o < NB; o <<= 1) {
        int a = (t >= o) ? off[t - o] : 0;
        __syncthreads();
        off[t] += a;
        __syncthreads();
    }
    int excl = off[t] - v;
    // snapshot global cursor (disjoint run within bucket region)
    gsnap[t] = atomicAdd(&cur[t], v);
    __syncthreads();
    off[t]  = excl;
    lcur[t] = excl;
    __syncthreads();
    // pass 2: scatter into LDS staging (bucket-grouped)
    for (int e = e0 + t; e < e1; e += 512) {
        int d = dst[e];
        int bq = d / NPBK;
        int p = atomicAdd(&lcur[bq], 1);
        stg[p] = (unsigned)src[e] | ((unsigned)(d - bq * NPBK) << 18);
    }
    __syncthreads();
    // writeout: one wave per bucket run, coalesced
    int wave = t >> 6, lane = t & 63;
    for (int bb = wave; bb < NB; bb += 8) {
        int o = off[bb];
        int c = lcur[bb] - o;
        int gb = gsnap[bb];
        for (int k = lane; k < c; k += 64)
            ed[gb + k] = stg[o + k];
    }
}

// ---------- phase B2: per-bucket counting sort, LDS-staged coalesced csr write ----------
__global__ void k_csr2(const unsigned* __restrict__ ed, const int* __restrict__ base,
                       int* __restrict__ rs, int* __restrict__ csr,
                       float* __restrict__ disq) {
    __shared__ int cnt[NB];
    __shared__ int scn[NB];
    __shared__ int stg[CAP];         // 46 KB staging
    int j = blockIdx.x, t = threadIdx.x;
    cnt[t] = 0;
    __syncthreads();
    int e0 = base[j], e1 = base[j + 1];
    int m = e1 - e0;
    for (int e = e0 + t; e < e1; e += 512)
        atomicAdd(&cnt[ed[e] >> 18], 1);
    __syncthreads();
    int v = cnt[t];
    scn[t] = v;
    __syncthreads();
    for (int off = 1; off < NB; off <<= 1) {
        int a = (t >= off) ? scn[t - off] : 0;
        __syncthreads();
        scn[t] += a;
        __syncthreads();
    }
    int excl = scn[t] - v;
    int n0 = j * NPBK;
    int n = n0 + t;
    if (t < NPBK && n < NN) {
        rs[n] = e0 + excl;
        disq[n] = rsqrtf((float)(v + 1));        // +1 self-loop
    }
    cnt[t] = excl;                               // cursors
    __syncthreads();
    if (m <= CAP) {
        for (int e = e0 + t; e < e1; e += 512) {
            unsigned ee = ed[e];
            int p = atomicAdd(&cnt[ee >> 18], 1);
            stg[p] = (int)(ee & 0x3FFFFu);
        }
        __syncthreads();
        for (int k = t; k < m; k += 512) csr[e0 + k] = stg[k];   // coalesced
    } else {
        for (int e = e0 + t; e < e1; e += 512) {
            unsigned ee = ed[e];
            int p = atomicAdd(&cnt[ee >> 18], 1);
            csr[e0 + p] = (int)(ee & 0x3FFFFu);
        }
    }
    if (j == 0 && t == 0) rs[NN] = NE;
}

// ---------- y = (x @ W1) * disq  -> bf16 ----------
__global__ void k_xw1(const float* __restrict__ x, const float* __restrict__ W1,
                      const float* __restrict__ disq, unsigned short* __restrict__ y) {
    __shared__ float w[4 * H];
    if (threadIdx.x < 4 * H) w[threadIdx.x] = W1[threadIdx.x];
    __syncthreads();
    int i = blockIdx.x * blockDim.x + threadIdx.x;
    if (i >= NN) return;
    float4 xv = ((const float4*)x)[i];
    float d = disq[i];
    float o[H];
#pragma unroll
    for (int h = 0; h < H; ++h)
        o[h] = (xv.x * w[0*H + h] + xv.y * w[1*H + h] +
                xv.z * w[2*H + h] + xv.w * w[3*H + h]) * d;
    unsigned pk[8];
#pragma unroll
    for (int q = 0; q < 8; ++q)
        pk[q] = (unsigned)f2bf(o[2*q]) | ((unsigned)f2bf(o[2*q+1]) << 16);
    uint4* yp = (uint4*)(y + (size_t)i * H);
    yp[0] = make_uint4(pk[0], pk[1], pk[2], pk[3]);
    yp[1] = make_uint4(pk[4], pk[5], pk[6], pk[7]);
}

// ---------- gather: 16 lanes/node, 8-way unrolled for MLP ----------
__global__ void k_gather(const int* __restrict__ rs, const int* __restrict__ csr,
                         const unsigned short* __restrict__ y, const float* __restrict__ disq,
                         const float* __restrict__ b, float* __restrict__ hout) {
    int n    = blockIdx.x * 16 + (threadIdx.x >> 4);
    int lane = threadIdx.x & 15;
    if (n >= NN) return;
    int s0 = rs[n], s1 = rs[n + 1];
    float acc = bf2f(y[(size_t)n * H + lane]);   // self-loop term
    int k = s0;
    for (; k + 8 <= s1; k += 8) {
        int sa = csr[k+0], sb = csr[k+1], sc = csr[k+2], sd = csr[k+3];
        int se = csr[k+4], sf = csr[k+5], sg = csr[k+6], sh = csr[k+7];
        float v0 = bf2f(y[(size_t)sa * H + lane]);
        float v1 = bf2f(y[(size_t)sb * H + lane]);
        float v2 = bf2f(y[(size_t)sc * H + lane]);
        float v3 = bf2f(y[(size_t)sd * H + lane]);
        float v4 = bf2f(y[(size_t)se * H + lane]);
        float v5 = bf2f(y[(size_t)sf * H + lane]);
        float v6 = bf2f(y[(size_t)sg * H + lane]);
        float v7 = bf2f(y[(size_t)sh * H + lane]);
        acc += ((v0 + v1) + (v2 + v3)) + ((v4 + v5) + (v6 + v7));
    }
    for (; k < s1; ++k) acc += bf2f(y[(size_t)csr[k] * H + lane]);
    hout[(size_t)n * H + lane] = fmaxf(fmaf(acc, disq[n], b[lane]), 0.f);
}

// ---------- y = (h @ W2) * disq -> bf16 ----------
__global__ void k_hw2(const float* __restrict__ hin, const float* __restrict__ W2,
                      const float* __restrict__ disq, unsigned short* __restrict__ yout) {
    __shared__ float w[H * H];
    if (threadIdx.x < H * H) w[threadIdx.x] = W2[threadIdx.x];
    __syncthreads();
    int i = blockIdx.x * blockDim.x + threadIdx.x;
    if (i >= NN) return;
    float hv[H];
    const float4* hp = (const float4*)(hin + (size_t)i * H);
#pragma unroll
    for (int q = 0; q < 4; ++q) ((float4*)hv)[q] = hp[q];
    float d = disq[i];
    float o[H];
#pragma unroll
    for (int h = 0; h < H; ++h) {
        float s = 0.f;
#pragma unroll
        for (int k = 0; k < H; ++k) s += hv[k] * w[k*H + h];
        o[h] = s * d;
    }
    unsigned pk[8];
#pragma unroll
    for (int q = 0; q < 8; ++q)
        pk[q] = (unsigned)f2bf(o[2*q]) | ((unsigned)f2bf(o[2*q+1]) << 16);
    uint4* yp = (uint4*)(yout + (size_t)i * H);
    yp[0] = make_uint4(pk[0], pk[1], pk[2], pk[3]);
    yp[1] = make_uint4(pk[4], pk[5], pk[6], pk[7]);
}

// ---------- pool: one block per graph, 16 groups x 16 lanes + LDS tree ----------
__global__ void k_pool_blk(const float* __restrict__ h, const int* __restrict__ batch,
                           float* __restrict__ gout) {
    __shared__ float red[16][H + 1];
    int g    = blockIdx.x;
    int lane = threadIdx.x & 15;
    int grp  = threadIdx.x >> 4;                 // 0..15
    int lo = 0, hi = NN;
    while (lo < hi) { int m = (lo + hi) >> 1; if (batch[m] < g) lo = m + 1; else hi = m; }
    int start = lo;
    hi = NN;
    while (lo < hi) { int m = (lo + hi) >> 1; if (batch[m] < g + 1) lo = m + 1; else hi = m; }
    int end = lo;
    float acc = 0.f;
    for (int i = start + grp; i < end; i += 16)
        acc += h[(size_t)i * H + lane];
    red[grp][lane] = acc;
    __syncthreads();
    if (grp < 8) red[grp][lane] += red[grp + 8][lane];
    __syncthreads();
    if (grp < 4) red[grp][lane] += red[grp + 4][lane];
    __syncthreads();
    if (grp < 2) red[grp][lane] += red[grp + 2][lane];
    __syncthreads();
    if (grp == 0)
        gout[(size_t)g * H + lane] = red[0][lane] + red[1][lane];
}

// ---------- final MLP ----------
__global__ void k_mlp(const float* __restrict__ g, const float* __restrict__ Wf1,
                      const float* __restrict__ bf1, const float* __restrict__ Wf2,
                      const float* __restrict__ bf2, float* __restrict__ out) {
    __shared__ float w1[H * H];
    __shared__ float b1s[H];
    __shared__ float w2[H];
    __shared__ float b2s;
    if (threadIdx.x < H * H) w1[threadIdx.x] = Wf1[threadIdx.x];
    if (threadIdx.x < H) { b1s[threadIdx.x] = bf1[threadIdx.x]; w2[threadIdx.x] = Wf2[threadIdx.x]; }
    if (threadIdx.x == 0) b2s = bf2[0];
    __syncthreads();
    int i = blockIdx.x * blockDim.x + threadIdx.x;
    if (i >= NG) return;
    float gv[H];
    const float4* gp = (const float4*)(g + (size_t)i * H);
#pragma unroll
    for (int q = 0; q < 4; ++q) ((float4*)gv)[q] = gp[q];
    float s2 = 0.f;
#pragma unroll
    for (int h = 0; h < H; ++h) {
        float t = b1s[h];
#pragma unroll
        for (int k = 0; k < H; ++k) t += gv[k] * w1[k*H + h];
        s2 += fmaxf(t, 0.f) * w2[h];
    }
    out[i] = s2 + b2s;
}

// ================= fallback (baseline atomic path, f32) =================
__global__ void k_deg_init(float* __restrict__ deg) {
    int i = blockIdx.x * blockDim.x + threadIdx.x;
    if (i < NN) deg[i] = 1.0f;
}
__global__ void k_deg_edges(const int* __restrict__ dst, float* __restrict__ deg) {
    int i = blockIdx.x * blockDim.x + threadIdx.x;
    if (i < NE) atomicAdd(&deg[dst[i]], 1.0f);
}
__global__ void k_disq(float* __restrict__ deg) {
    int i = blockIdx.x * blockDim.x + threadIdx.x;
    if (i < NN) deg[i] = rsqrtf(deg[i]);
}
__global__ void k_xw1f(const float* __restrict__ x, const float* __restrict__ W1,
                       const float* __restrict__ disq, float* __restrict__ y) {
    __shared__ float w[4 * H];
    if (threadIdx.x < 4 * H) w[threadIdx.x] = W1[threadIdx.x];
    __syncthreads();
    int i = blockIdx.x * blockDim.x + threadIdx.x;
    if (i >= NN) return;
    float4 xv = ((const float4*)x)[i];
    float d = disq[i];
    float o[H];
#pragma unroll
    for (int h = 0; h < H; ++h)
        o[h] = (xv.x * w[0*H + h] + xv.y * w[1*H + h] +
                xv.z * w[2*H + h] + xv.w * w[3*H + h]) * d;
    float4* yp = (float4*)(y + (size_t)i * H);
#pragma unroll
    for (int q = 0; q < 4; ++q) yp[q] = ((float4*)o)[q];
}
__global__ void k_hw2f(const float* __restrict__ hin, const float* __restrict__ W2,
                       const float* __restrict__ disq, float* __restrict__ yout) {
    __shared__ float w[H * H];
    if (threadIdx.x < H * H) w[threadIdx.x] = W2[threadIdx.x];
    __syncthreads();
    int i = blockIdx.x * blockDim.x + threadIdx.x;
    if (i >= NN) return;
    float hv[H];
    const float4* hp = (const float4*)(hin + (size_t)i * H);
#pragma unroll
    for (int q = 0; q < 4; ++q) ((float4*)hv)[q] = hp[q];
    float d = disq[i];
    float o[H];
#pragma unroll
    for (int h = 0; h < H; ++h) {
        float s = 0.f;
#pragma unroll
        for (int k = 0; k < H; ++k) s += hv[k] * w[k*H + h];
        o[h] = s * d;
    }
    float4* yp = (float4*)(yout + (size_t)i * H);
#pragma unroll
    for (int q = 0; q < 4; ++q) yp[q] = ((float4*)o)[q];
}
__global__ void k_scatter(const int* __restrict__ src, const int* __restrict__ dst,
                          const float* __restrict__ y, float* __restrict__ acc) {
    int i = blockIdx.x * blockDim.x + threadIdx.x;
    if (i >= NE) return;
    int s = src[i], d = dst[i];
    const float4* yp = (const float4*)(y + (size_t)s * H);
    float* ap = acc + (size_t)d * H;
#pragma unroll
    for (int q = 0; q < 4; ++q) {
        float4 v = yp[q];
        atomicAdd(ap + q*4 + 0, v.x);
        atomicAdd(ap + q*4 + 1, v.y);
        atomicAdd(ap + q*4 + 2, v.z);
        atomicAdd(ap + q*4 + 3, v.w);
    }
}
__global__ void k_post(const float* __restrict__ acc, const float* __restrict__ disq,
                       const float* __restrict__ b, float* __restrict__ hout) {
    __shared__ float bs[H];
    if (threadIdx.x < H) bs[threadIdx.x] = b[threadIdx.x];
    __syncthreads();
    int i = blockIdx.x * blockDim.x + threadIdx.x;
    if (i >= NN) return;
    float d = disq[i];
    const float4* ap = (const float4*)(acc + (size_t)i * H);
    float4* hp = (float4*)(hout + (size_t)i * H);
#pragma unroll
    for (int q = 0; q < 4; ++q) {
        float4 v = ap[q];
        float4 r;
        r.x = fmaxf(v.x * d + bs[q*4+0], 0.f);
        r.y = fmaxf(v.y * d + bs[q*4+1], 0.f);
        r.z = fmaxf(v.z * d + bs[q*4+2], 0.f);
        r.w = fmaxf(v.w * d + bs[q*4+3], 0.f);
        hp[q] = r;
    }
}

extern "C" void kernel_launch(void* const* d_in, const int* in_sizes, int n_in,
                              void* d_out, int out_size, void* d_ws, size_t ws_size,
                              hipStream_t stream) {
    const float* x   = (const float*)d_in[0];
    const float* W1  = (const float*)d_in[1];
    const float* b1  = (const float*)d_in[2];
    const float* W2  = (const float*)d_in[3];
    const float* b2  = (const float*)d_in[4];
    const float* Wf1 = (const float*)d_in[5];
    const float* bf1 = (const float*)d_in[6];
    const float* Wf2 = (const float*)d_in[7];
    const float* bf2 = (const float*)d_in[8];
    const int*   ei    = (const int*)d_in[9];
    const int*   batch = (const int*)d_in[10];
    const int* src = ei;        // edge_index row 0
    const int* dst = ei + NE;   // edge_index row 1
    float* out = (float*)d_out;

    const int BT  = 256;
    const int gbN = (NN + BT - 1) / BT;               // 586
    const int gbE = (NE + BT - 1) / BT;               // 18750 (fallback)
    const int NPB = BT / H;                           // 16
    const int gbG = (NN + NPB - 1) / NPB;             // 9375 gather blocks

    // ---- workspace layout (4-byte words; region starts 16B-aligned) ----
    // tot[512] | base[513]pad | cur[512] | ed[NE] | csr[NE] | rs[NN+1]pad |
    // disq[NN] | ybf[NN*H bf16] | bufB[NN*H f32] | g[NG*H]
    size_t need = ((size_t)13509748) * 4;   // ~54.0 MB
    if (ws_size >= need) {
        int*      tot  = (int*)d_ws;                   // 512
        int*      base = tot + 512;                    // 513 (pad to 1040)
        int*      cur  = tot + 1040;                   // 512
        unsigned* ed   = (unsigned*)(tot + 1552);      // NE
        int*      csr  = tot + 4801552;                // NE
        int*      rs   = tot + 9601552;                // NN+1 (pad to 9751556)
        float*    disq = (float*)(tot + 9751556);      // NN
        unsigned short* ybf = (unsigned short*)(tot + 9901556); // NN*H bf16
        float*    bufB = (float*)(tot + 11101556);     // NN*H
        float*    g    = (float*)(tot + 13501556);     // NG*H

        // graph bucketing (LDS-staged partition) + counting sort -> CSR
        hipMemsetAsync(tot, 0, NB * sizeof(int), stream);
        k_hist2 <<<NBLK, 512, 0, stream>>>(dst, tot);
        k_scant2<<<1,    NB,  0, stream>>>(tot, base, cur);
        k_part  <<<NBLK, 512, 0, stream>>>(src, dst, cur, ed);
        k_csr2  <<<NB,   512, 0, stream>>>(ed, base, rs, csr, disq);

        // conv1
        k_xw1   <<<gbN, 256, 0, stream>>>(x, W1, disq, ybf);
        k_gather<<<gbG, 256, 0, stream>>>(rs, csr, ybf, disq, b1, bufB);   // h1
        // conv2
        k_hw2   <<<gbN, 256, 0, stream>>>(bufB, W2, disq, ybf);            // y2
        k_gather<<<gbG, 256, 0, stream>>>(rs, csr, ybf, disq, b2, bufB);   // h2
        // pool + MLP
        k_pool_blk<<<NG, 256, 0, stream>>>(bufB, batch, g);
        k_mlp<<<1, 512, 0, stream>>>(g, Wf1, bf1, Wf2, bf2, out);
    } else {
        // fallback: baseline atomic-scatter path (~20 MB ws, f32)
        float* disq = (float*)d_ws;
        float* bufA = disq + NN;
        float* bufB = bufA + (size_t)NN * H;
        float* g    = bufB + (size_t)NN * H;

        k_deg_init<<<gbN, BT, 0, stream>>>(disq);
        k_deg_edges<<<gbE, BT, 0, stream>>>(dst, disq);
        k_disq<<<gbN, BT, 0, stream>>>(disq);

        k_xw1f<<<gbN, BT, 0, stream>>>(x, W1, disq, bufA);
        hipMemcpyAsync(bufB, bufA, (size_t)NN * H * sizeof(float),
                       hipMemcpyDeviceToDevice, stream);
        k_scatter<<<gbE, BT, 0, stream>>>(src, dst, bufA, bufB);
        k_post<<<gbN, BT, 0, stream>>>(bufB, disq, b1, bufA);

        k_hw2f<<<gbN, BT, 0, stream>>>(bufA, W2, disq, bufB);
        hipMemcpyAsync(bufA, bufB, (size_t)NN * H * sizeof(float),
                       hipMemcpyDeviceToDevice, stream);
        k_scatter<<<gbE, BT, 0, stream>>>(src, dst, bufB, bufA);
        k_post<<<gbN, BT, 0, stream>>>(bufA, disq, b2, bufB);

        k_pool_blk<<<NG, BT, 0, stream>>>(bufB, batch, g);
        k_mlp<<<1, 512, 0, stream>>>(g, Wf1, bf1, Wf2, bf2, out);
    }
}

// Round 16
// 197.981 us; speedup vs baseline: 5.1114x; 1.1331x over previous
//
#include <hip/hip_runtime.h>

constexpr int NN = 150000;   // nodes
constexpr int NE = 4800000;  // edges
constexpr int NG = 512;      // graphs
constexpr int H  = 16;       // hidden
constexpr int NB   = 512;    // coarse dst-buckets
constexpr int NPBK = 293;    // nodes per bucket (512*293 = 150016 >= NN)
constexpr int NBLK = 512;    // streaming blocks for hist/part
constexpr int CHUNK = NE / NBLK;   // 9375 edges per block (exact)
constexpr int CAP = 11776;   // k_csr2 LDS staging capacity (mean 9375, +24 sigma)

__device__ inline unsigned short f2bf(float f) {
    union { float f; unsigned u; } v; v.f = f;
    unsigned r = v.u + 0x7FFFu + ((v.u >> 16) & 1u);   // RNE
    return (unsigned short)(r >> 16);
}
__device__ inline float bf2f(unsigned short s) {
    union { unsigned u; float f; } v; v.u = ((unsigned)s) << 16;
    return v.f;
}

// ---------- phase A: per-block LDS histogram -> mat[b][bucket] ----------
__global__ void k_hist2(const int* __restrict__ dst, int* __restrict__ mat) {
    __shared__ int cnt[NB];
    cnt[threadIdx.x] = 0;
    __syncthreads();
    int b = blockIdx.x;
    int e0 = b * CHUNK, e1 = e0 + CHUNK;
    for (int e = e0 + (int)threadIdx.x; e < e1; e += 512)
        atomicAdd(&cnt[dst[e] / NPBK], 1);
    __syncthreads();
    mat[b * NB + threadIdx.x] = cnt[threadIdx.x];
}

// ---------- column scan: mat[:,j] -> exclusive prefix (in place), totals ----------
__global__ void k_scanb(int* __restrict__ mat, int* __restrict__ tot) {
    __shared__ int tmp[NBLK];
    int j = blockIdx.x, t = threadIdx.x;
    int v = mat[t * NB + j];
    tmp[t] = v;
    __syncthreads();
    for (int off = 1; off < NBLK; off <<= 1) {
        int a = (t >= off) ? tmp[t - off] : 0;
        __syncthreads();
        tmp[t] += a;
        __syncthreads();
    }
    mat[t * NB + j] = tmp[t] - v;               // exclusive within column
    if (t == NBLK - 1) tot[j] = tmp[t];
}

// ---------- bucket base scan (exclusive over NB buckets) ----------
__global__ void k_scant(const int* __restrict__ tot, int* __restrict__ base) {
    __shared__ int tmp[NB];
    int t = threadIdx.x;
    int v = tot[t];
    tmp[t] = v;
    __syncthreads();
    for (int off = 1; off < NB; off <<= 1) {
        int a = (t >= off) ? tmp[t - off] : 0;
        __syncthreads();
        tmp[t] += a;
        __syncthreads();
    }
    base[t] = tmp[t] - v;
    if (t == 0) base[NB] = NE;
}

// ---------- phase B: LDS-staged partition (counts from mat), coalesced writeout ----------
__global__ void k_part2(const int* __restrict__ src, const int* __restrict__ dst,
                        const int* __restrict__ mat, const int* __restrict__ tot,
                        const int* __restrict__ base, unsigned* __restrict__ ed) {
    __shared__ int off[NB];          // exclusive local offsets
    __shared__ int gsnap[NB];        // global run base per bucket
    __shared__ int lcur[NB];         // local scatter cursors
    __shared__ unsigned stg[CHUNK];  // 37.5 KB staging
    int b = blockIdx.x, t = threadIdx.x;
    int e0 = b * CHUNK, e1 = e0 + CHUNK;
    int exg = mat[b * NB + t];                       // col-exclusive (blocks < b)
    int nxt = (b + 1 < NBLK) ? mat[(b + 1) * NB + t] : tot[t];
    int v = nxt - exg;                               // my count for bucket t
    gsnap[t] = base[t] + exg;
    off[t] = v;
    __syncthreads();
    for (int o = 1; o < NB; o <<= 1) {
        int a = (t >= o) ? off[t - o] : 0;
        __syncthreads();
        off[t] += a;
        __syncthreads();
    }
    int excl = off[t] - v;
    __syncthreads();
    off[t]  = excl;
    lcur[t] = excl;
    __syncthreads();
    // scatter into LDS staging (bucket-grouped)
    for (int e = e0 + t; e < e1; e += 512) {
        int d = dst[e];
        int bq = d / NPBK;
        int p = atomicAdd(&lcur[bq], 1);
        stg[p] = (unsigned)src[e] | ((unsigned)(d - bq * NPBK) << 18);
    }
    __syncthreads();
    // writeout: one wave per bucket run, coalesced
    int wave = t >> 6, lane = t & 63;
    for (int bb = wave; bb < NB; bb += 8) {
        int o = off[bb];
        int c = lcur[bb] - o;
        int gb = gsnap[bb];
        for (int k = lane; k < c; k += 64)
            ed[gb + k] = stg[o + k];
    }
}

// ---------- phase B2: per-bucket counting sort, LDS-staged coalesced csr write ----------
__global__ void k_csr2(const unsigned* __restrict__ ed, const int* __restrict__ base,
                       int* __restrict__ rs, int* __restrict__ csr,
                       float* __restrict__ disq) {
    __shared__ int cnt[NB];
    __shared__ int scn[NB];
    __shared__ int stg[CAP];         // 46 KB staging
    int j = blockIdx.x, t = threadIdx.x;
    cnt[t] = 0;
    __syncthreads();
    int e0 = base[j], e1 = base[j + 1];
    int m = e1 - e0;
    for (int e = e0 + t; e < e1; e += 512)
        atomicAdd(&cnt[ed[e] >> 18], 1);
    __syncthreads();
    int v = cnt[t];
    scn[t] = v;
    __syncthreads();
    for (int off = 1; off < NB; off <<= 1) {
        int a = (t >= off) ? scn[t - off] : 0;
        __syncthreads();
        scn[t] += a;
        __syncthreads();
    }
    int excl = scn[t] - v;
    int n0 = j * NPBK;
    int n = n0 + t;
    if (t < NPBK && n < NN) {
        rs[n] = e0 + excl;
        disq[n] = rsqrtf((float)(v + 1));        // +1 self-loop
    }
    cnt[t] = excl;                               // cursors
    __syncthreads();
    if (m <= CAP) {
        for (int e = e0 + t; e < e1; e += 512) {
            unsigned ee = ed[e];
            int p = atomicAdd(&cnt[ee >> 18], 1);
            stg[p] = (int)(ee & 0x3FFFFu);
        }
        __syncthreads();
        for (int k = t; k < m; k += 512) csr[e0 + k] = stg[k];   // coalesced
    } else {
        for (int e = e0 + t; e < e1; e += 512) {
            unsigned ee = ed[e];
            int p = atomicAdd(&cnt[ee >> 18], 1);
            csr[e0 + p] = (int)(ee & 0x3FFFFu);
        }
    }
    if (j == 0 && t == 0) rs[NN] = NE;
}

// ---------- y = (x @ W1) * disq  -> bf16 ----------
__global__ void k_xw1(const float* __restrict__ x, const float* __restrict__ W1,
                      const float* __restrict__ disq, unsigned short* __restrict__ y) {
    __shared__ float w[4 * H];
    if (threadIdx.x < 4 * H) w[threadIdx.x] = W1[threadIdx.x];
    __syncthreads();
    int i = blockIdx.x * blockDim.x + threadIdx.x;
    if (i >= NN) return;
    float4 xv = ((const float4*)x)[i];
    float d = disq[i];
    float o[H];
#pragma unroll
    for (int h = 0; h < H; ++h)
        o[h] = (xv.x * w[0*H + h] + xv.y * w[1*H + h] +
                xv.z * w[2*H + h] + xv.w * w[3*H + h]) * d;
    unsigned pk[8];
#pragma unroll
    for (int q = 0; q < 8; ++q)
        pk[q] = (unsigned)f2bf(o[2*q]) | ((unsigned)f2bf(o[2*q+1]) << 16);
    uint4* yp = (uint4*)(y + (size_t)i * H);
    yp[0] = make_uint4(pk[0], pk[1], pk[2], pk[3]);
    yp[1] = make_uint4(pk[4], pk[5], pk[6], pk[7]);
}

// ---------- gather: 16 lanes/node, 8-way unrolled for MLP ----------
__global__ void k_gather(const int* __restrict__ rs, const int* __restrict__ csr,
                         const unsigned short* __restrict__ y, const float* __restrict__ disq,
                         const float* __restrict__ b, float* __restrict__ hout) {
    int n    = blockIdx.x * 16 + (threadIdx.x >> 4);
    int lane = threadIdx.x & 15;
    if (n >= NN) return;
    int s0 = rs[n], s1 = rs[n + 1];
    float acc = bf2f(y[(size_t)n * H + lane]);   // self-loop term
    int k = s0;
    for (; k + 8 <= s1; k += 8) {
        int sa = csr[k+0], sb = csr[k+1], sc = csr[k+2], sd = csr[k+3];
        int se = csr[k+4], sf = csr[k+5], sg = csr[k+6], sh = csr[k+7];
        float v0 = bf2f(y[(size_t)sa * H + lane]);
        float v1 = bf2f(y[(size_t)sb * H + lane]);
        float v2 = bf2f(y[(size_t)sc * H + lane]);
        float v3 = bf2f(y[(size_t)sd * H + lane]);
        float v4 = bf2f(y[(size_t)se * H + lane]);
        float v5 = bf2f(y[(size_t)sf * H + lane]);
        float v6 = bf2f(y[(size_t)sg * H + lane]);
        float v7 = bf2f(y[(size_t)sh * H + lane]);
        acc += ((v0 + v1) + (v2 + v3)) + ((v4 + v5) + (v6 + v7));
    }
    for (; k < s1; ++k) acc += bf2f(y[(size_t)csr[k] * H + lane]);
    hout[(size_t)n * H + lane] = fmaxf(fmaf(acc, disq[n], b[lane]), 0.f);
}

// ---------- y = (h @ W2) * disq -> bf16 ----------
__global__ void k_hw2(const float* __restrict__ hin, const float* __restrict__ W2,
                      const float* __restrict__ disq, unsigned short* __restrict__ yout) {
    __shared__ float w[H * H];
    if (threadIdx.x < H * H) w[threadIdx.x] = W2[threadIdx.x];
    __syncthreads();
    int i = blockIdx.x * blockDim.x + threadIdx.x;
    if (i >= NN) return;
    float hv[H];
    const float4* hp = (const float4*)(hin + (size_t)i * H);
#pragma unroll
    for (int q = 0; q < 4; ++q) ((float4*)hv)[q] = hp[q];
    float d = disq[i];
    float o[H];
#pragma unroll
    for (int h = 0; h < H; ++h) {
        float s = 0.f;
#pragma unroll
        for (int k = 0; k < H; ++k) s += hv[k] * w[k*H + h];
        o[h] = s * d;
    }
    unsigned pk[8];
#pragma unroll
    for (int q = 0; q < 8; ++q)
        pk[q] = (unsigned)f2bf(o[2*q]) | ((unsigned)f2bf(o[2*q+1]) << 16);
    uint4* yp = (uint4*)(yout + (size_t)i * H);
    yp[0] = make_uint4(pk[0], pk[1], pk[2], pk[3]);
    yp[1] = make_uint4(pk[4], pk[5], pk[6], pk[7]);
}

// ---------- pool: one block per graph, 16 groups x 16 lanes + LDS tree ----------
__global__ void k_pool_blk(const float* __restrict__ h, const int* __restrict__ batch,
                           float* __restrict__ gout) {
    __shared__ float red[16][H + 1];
    int g    = blockIdx.x;
    int lane = threadIdx.x & 15;
    int grp  = threadIdx.x >> 4;                 // 0..15
    int lo = 0, hi = NN;
    while (lo < hi) { int m = (lo + hi) >> 1; if (batch[m] < g) lo = m + 1; else hi = m; }
    int start = lo;
    hi = NN;
    while (lo < hi) { int m = (lo + hi) >> 1; if (batch[m] < g + 1) lo = m + 1; else hi = m; }
    int end = lo;
    float acc = 0.f;
    for (int i = start + grp; i < end; i += 16)
        acc += h[(size_t)i * H + lane];
    red[grp][lane] = acc;
    __syncthreads();
    if (grp < 8) red[grp][lane] += red[grp + 8][lane];
    __syncthreads();
    if (grp < 4) red[grp][lane] += red[grp + 4][lane];
    __syncthreads();
    if (grp < 2) red[grp][lane] += red[grp + 2][lane];
    __syncthreads();
    if (grp == 0)
        gout[(size_t)g * H + lane] = red[0][lane] + red[1][lane];
}

// ---------- final MLP ----------
__global__ void k_mlp(const float* __restrict__ g, const float* __restrict__ Wf1,
                      const float* __restrict__ bf1, const float* __restrict__ Wf2,
                      const float* __restrict__ bf2, float* __restrict__ out) {
    __shared__ float w1[H * H];
    __shared__ float b1s[H];
    __shared__ float w2[H];
    __shared__ float b2s;
    if (threadIdx.x < H * H) w1[threadIdx.x] = Wf1[threadIdx.x];
    if (threadIdx.x < H) { b1s[threadIdx.x] = bf1[threadIdx.x]; w2[threadIdx.x] = Wf2[threadIdx.x]; }
    if (threadIdx.x == 0) b2s = bf2[0];
    __syncthreads();
    int i = blockIdx.x * blockDim.x + threadIdx.x;
    if (i >= NG) return;
    float gv[H];
    const float4* gp = (const float4*)(g + (size_t)i * H);
#pragma unroll
    for (int q = 0; q < 4; ++q) ((float4*)gv)[q] = gp[q];
    float s2 = 0.f;
#pragma unroll
    for (int h = 0; h < H; ++h) {
        float t = b1s[h];
#pragma unroll
        for (int k = 0; k < H; ++k) t += gv[k] * w1[k*H + h];
        s2 += fmaxf(t, 0.f) * w2[h];
    }
    out[i] = s2 + b2s;
}

// ================= fallback (baseline atomic path, f32) =================
__global__ void k_deg_init(float* __restrict__ deg) {
    int i = blockIdx.x * blockDim.x + threadIdx.x;
    if (i < NN) deg[i] = 1.0f;
}
__global__ void k_deg_edges(const int* __restrict__ dst, float* __restrict__ deg) {
    int i = blockIdx.x * blockDim.x + threadIdx.x;
    if (i < NE) atomicAdd(&deg[dst[i]], 1.0f);
}
__global__ void k_disq(float* __restrict__ deg) {
    int i = blockIdx.x * blockDim.x + threadIdx.x;
    if (i < NN) deg[i] = rsqrtf(deg[i]);
}
__global__ void k_xw1f(const float* __restrict__ x, const float* __restrict__ W1,
                       const float* __restrict__ disq, float* __restrict__ y) {
    __shared__ float w[4 * H];
    if (threadIdx.x < 4 * H) w[threadIdx.x] = W1[threadIdx.x];
    __syncthreads();
    int i = blockIdx.x * blockDim.x + threadIdx.x;
    if (i >= NN) return;
    float4 xv = ((const float4*)x)[i];
    float d = disq[i];
    float o[H];
#pragma unroll
    for (int h = 0; h < H; ++h)
        o[h] = (xv.x * w[0*H + h] + xv.y * w[1*H + h] +
                xv.z * w[2*H + h] + xv.w * w[3*H + h]) * d;
    float4* yp = (float4*)(y + (size_t)i * H);
#pragma unroll
    for (int q = 0; q < 4; ++q) yp[q] = ((float4*)o)[q];
}
__global__ void k_hw2f(const float* __restrict__ hin, const float* __restrict__ W2,
                       const float* __restrict__ disq, float* __restrict__ yout) {
    __shared__ float w[H * H];
    if (threadIdx.x < H * H) w[threadIdx.x] = W2[threadIdx.x];
    __syncthreads();
    int i = blockIdx.x * blockDim.x + threadIdx.x;
    if (i >= NN) return;
    float hv[H];
    const float4* hp = (const float4*)(hin + (size_t)i * H);
#pragma unroll
    for (int q = 0; q < 4; ++q) ((float4*)hv)[q] = hp[q];
    float d = disq[i];
    float o[H];
#pragma unroll
    for (int h = 0; h < H; ++h) {
        float s = 0.f;
#pragma unroll
        for (int k = 0; k < H; ++k) s += hv[k] * w[k*H + h];
        o[h] = s * d;
    }
    float4* yp = (float4*)(yout + (size_t)i * H);
#pragma unroll
    for (int q = 0; q < 4; ++q) yp[q] = ((float4*)o)[q];
}
__global__ void k_scatter(const int* __restrict__ src, const int* __restrict__ dst,
                          const float* __restrict__ y, float* __restrict__ acc) {
    int i = blockIdx.x * blockDim.x + threadIdx.x;
    if (i >= NE) return;
    int s = src[i], d = dst[i];
    const float4* yp = (const float4*)(y + (size_t)s * H);
    float* ap = acc + (size_t)d * H;
#pragma unroll
    for (int q = 0; q < 4; ++q) {
        float4 v = yp[q];
        atomicAdd(ap + q*4 + 0, v.x);
        atomicAdd(ap + q*4 + 1, v.y);
        atomicAdd(ap + q*4 + 2, v.z);
        atomicAdd(ap + q*4 + 3, v.w);
    }
}
__global__ void k_post(const float* __restrict__ acc, const float* __restrict__ disq,
                       const float* __restrict__ b, float* __restrict__ hout) {
    __shared__ float bs[H];
    if (threadIdx.x < H) bs[threadIdx.x] = b[threadIdx.x];
    __syncthreads();
    int i = blockIdx.x * blockDim.x + threadIdx.x;
    if (i >= NN) return;
    float d = disq[i];
    const float4* ap = (const float4*)(acc + (size_t)i * H);
    float4* hp = (float4*)(hout + (size_t)i * H);
#pragma unroll
    for (int q = 0; q < 4; ++q) {
        float4 v = ap[q];
        float4 r;
        r.x = fmaxf(v.x * d + bs[q*4+0], 0.f);
        r.y = fmaxf(v.y * d + bs[q*4+1], 0.f);
        r.z = fmaxf(v.z * d + bs[q*4+2], 0.f);
        r.w = fmaxf(v.w * d + bs[q*4+3], 0.f);
        hp[q] = r;
    }
}

extern "C" void kernel_launch(void* const* d_in, const int* in_sizes, int n_in,
                              void* d_out, int out_size, void* d_ws, size_t ws_size,
                              hipStream_t stream) {
    const float* x   = (const float*)d_in[0];
    const float* W1  = (const float*)d_in[1];
    const float* b1  = (const float*)d_in[2];
    const float* W2  = (const float*)d_in[3];
    const float* b2  = (const float*)d_in[4];
    const float* Wf1 = (const float*)d_in[5];
    const float* bf1 = (const float*)d_in[6];
    const float* Wf2 = (const float*)d_in[7];
    const float* bf2 = (const float*)d_in[8];
    const int*   ei    = (const int*)d_in[9];
    const int*   batch = (const int*)d_in[10];
    const int* src = ei;        // edge_index row 0
    const int* dst = ei + NE;   // edge_index row 1
    float* out = (float*)d_out;

    const int BT  = 256;
    const int gbN = (NN + BT - 1) / BT;               // 586
    const int gbE = (NE + BT - 1) / BT;               // 18750 (fallback)
    const int NPB = BT / H;                           // 16
    const int gbG = (NN + NPB - 1) / NPB;             // 9375 gather blocks

    // ---- workspace layout (4-byte words; region starts 16B-aligned) ----
    // mat[512*512] | tot[512] | base[513]pad | ed[NE] | csr[NE] | rs[NN+1]pad |
    // disq[NN] | ybf[NN*H bf16] | bufB[NN*H f32] | g[NG*H]
    size_t need = ((size_t)13771368) * 4;   // ~55.1 MB
    if (ws_size >= need) {
        int*      mat  = (int*)d_ws;                   // 262144
        int*      tot  = mat + 262144;                 // 512
        int*      base = mat + 262656;                 // 513 (pad to 263172)
        unsigned* ed   = (unsigned*)(mat + 263172);    // NE
        int*      csr  = mat + 5063172;                // NE
        int*      rs   = mat + 9863172;                // NN+1 (pad to 10013176)
        float*    disq = (float*)(mat + 10013176);     // NN
        unsigned short* ybf = (unsigned short*)(mat + 10163176); // NN*H bf16
        float*    bufB = (float*)(mat + 11363176);     // NN*H
        float*    g    = (float*)(mat + 13763176);     // NG*H

        // graph bucketing (mat-driven, no count pass in part) -> CSR
        k_hist2<<<NBLK, 512, 0, stream>>>(dst, mat);
        k_scanb<<<NB,   NBLK, 0, stream>>>(mat, tot);
        k_scant<<<1,    NB,  0, stream>>>(tot, base);
        k_part2<<<NBLK, 512, 0, stream>>>(src, dst, mat, tot, base, ed);
        k_csr2 <<<NB,   512, 0, stream>>>(ed, base, rs, csr, disq);

        // conv1
        k_xw1   <<<gbN, 256, 0, stream>>>(x, W1, disq, ybf);
        k_gather<<<gbG, 256, 0, stream>>>(rs, csr, ybf, disq, b1, bufB);   // h1
        // conv2
        k_hw2   <<<gbN, 256, 0, stream>>>(bufB, W2, disq, ybf);            // y2
        k_gather<<<gbG, 256, 0, stream>>>(rs, csr, ybf, disq, b2, bufB);   // h2
        // pool + MLP
        k_pool_blk<<<NG, 256, 0, stream>>>(bufB, batch, g);
        k_mlp<<<1, 512, 0, stream>>>(g, Wf1, bf1, Wf2, bf2, out);
    } else {
        // fallback: baseline atomic-scatter path (~20 MB ws, f32)
        float* disq = (float*)d_ws;
        float* bufA = disq + NN;
        float* bufB = bufA + (size_t)NN * H;
        float* g    = bufB + (size_t)NN * H;

        k_deg_init<<<gbN, BT, 0, stream>>>(disq);
        k_deg_edges<<<gbE, BT, 0, stream>>>(dst, disq);
        k_disq<<<gbN, BT, 0, stream>>>(disq);

        k_xw1f<<<gbN, BT, 0, stream>>>(x, W1, disq, bufA);
        hipMemcpyAsync(bufB, bufA, (size_t)NN * H * sizeof(float),
                       hipMemcpyDeviceToDevice, stream);
        k_scatter<<<gbE, BT, 0, stream>>>(src, dst, bufA, bufB);
        k_post<<<gbN, BT, 0, stream>>>(bufB, disq, b1, bufA);

        k_hw2f<<<gbN, BT, 0, stream>>>(bufA, W2, disq, bufB);
        hipMemcpyAsync(bufA, bufB, (size_t)NN * H * sizeof(float),
                       hipMemcpyDeviceToDevice, stream);
        k_scatter<<<gbE, BT, 0, stream>>>(src, dst, bufB, bufA);
        k_post<<<gbN, BT, 0, stream>>>(bufA, disq, b2, bufB);

        k_pool_blk<<<NG, BT, 0, stream>>>(bufB, batch, g);
        k_mlp<<<1, 512, 0, stream>>>(g, Wf1, bf1, Wf2, bf2, out);
    }
}